// Round 3
// baseline (2071.382 us; speedup 1.0000x reference)
//
#include <hip/hip_runtime.h>

typedef unsigned short u16;
typedef unsigned int   u32;

#define BN 8
#define CC 256
#define HW 96
#define NN 9216   // 96*96
#define KK 16

__device__ __forceinline__ float us2f(u16 u){
  union { u32 i; float f; } v; v.i = ((u32)u) << 16; return v.f;
}
__device__ __forceinline__ u16 f2us(float f){
  union { float f; u32 i; } v; v.f = f;
  u32 x = v.i;
  u32 r = (x + 0x7fffu + ((x >> 16) & 1u)) >> 16;  // RNE
  return (u16)r;
}
__device__ __forceinline__ float lrelu(float v){ return v >= 0.f ? v : 0.001f*v; }

// ---------------- K1: F = w_f.x ; Bm = lrelu(w_a2b.x) ; AM = [mean_c, max_c] ----------------
__global__ __launch_bounds__(256) void k1_fx(
    const float* __restrict__ x, const float* __restrict__ w_f, const float* __restrict__ w_a2b,
    float* __restrict__ F, float* __restrict__ AM, float* __restrict__ Bm)
{
  __shared__ float wf[CC][KK];   // [c][k]
  __shared__ float wa[CC];
  int t = threadIdx.x;
  for (int i = t; i < KK*CC; i += 256) wf[i & 255][i >> 8] = w_f[i];
  wa[t] = w_a2b[t];
  __syncthreads();
  int pid = blockIdx.x*256 + t;             // 2 pixels per thread
  int b = pid / (NN/2);
  int n = (pid % (NN/2)) * 2;
  const float* xp = x + (size_t)b*CC*NN + n;
  float a0[KK], a1[KK];
  #pragma unroll
  for (int k=0;k<KK;k++){ a0[k]=0.f; a1[k]=0.f; }
  float s0=0.f,s1=0.f,m0=-3e38f,m1=-3e38f,b0=0.f,b1=0.f;
  for (int c=0;c<CC;c++){
    float2 xv = *reinterpret_cast<const float2*>(xp + (size_t)c*NN);
    float v0 = xv.x, v1 = xv.y;
    s0 += v0; s1 += v1;
    m0 = fmaxf(m0, v0); m1 = fmaxf(m1, v1);
    b0 = fmaf(wa[c], v0, b0); b1 = fmaf(wa[c], v1, b1);
    const float* wr = wf[c];
    #pragma unroll
    for (int k=0;k<KK;k++){ a0[k] = fmaf(wr[k], v0, a0[k]); a1[k] = fmaf(wr[k], v1, a1[k]); }
  }
  float* Fp = F + (size_t)b*KK*NN + n;
  #pragma unroll
  for (int k=0;k<KK;k++){ float2 f2; f2.x=a0[k]; f2.y=a1[k];
    *reinterpret_cast<float2*>(Fp + (size_t)k*NN) = f2; }
  float2 av; av.x = s0*(1.f/256.f); av.y = s1*(1.f/256.f);
  float2 mx; mx.x = m0; mx.y = m1;
  *reinterpret_cast<float2*>(AM + (size_t)b*2*NN + n) = av;
  *reinterpret_cast<float2*>(AM + (size_t)b*2*NN + NN + n) = mx;
  float2 bm; bm.x = lrelu(b0); bm.y = lrelu(b1);
  *reinterpret_cast<float2*>(Bm + (size_t)b*NN + n) = bm;
}

// ---------------- K2: G[b,k,c] = sum_n F[b,k,n]*x[b,c,n]  (4 c per block) ----------------
__global__ __launch_bounds__(256) void k2_g(
    const float* __restrict__ x, const float* __restrict__ F, float* __restrict__ G)
{
  int b = blockIdx.x >> 6;
  int c0 = (blockIdx.x & 63) * 4;
  int t = threadIdx.x;
  const float* Fp = F + (size_t)b*KK*NN;
  const float* xp = x + ((size_t)b*CC + c0)*NN;
  float acc[KK][4];
  #pragma unroll
  for (int k=0;k<KK;k++){ acc[k][0]=acc[k][1]=acc[k][2]=acc[k][3]=0.f; }
  for (int n = t; n < NN; n += 256){
    float xv0 = xp[n];
    float xv1 = xp[(size_t)NN + n];
    float xv2 = xp[(size_t)2*NN + n];
    float xv3 = xp[(size_t)3*NN + n];
    #pragma unroll
    for (int k=0;k<KK;k++){
      float fv = Fp[(size_t)k*NN + n];
      acc[k][0] = fmaf(fv, xv0, acc[k][0]);
      acc[k][1] = fmaf(fv, xv1, acc[k][1]);
      acc[k][2] = fmaf(fv, xv2, acc[k][2]);
      acc[k][3] = fmaf(fv, xv3, acc[k][3]);
    }
  }
  #pragma unroll
  for (int k=0;k<KK;k++){
    #pragma unroll
    for (int i=0;i<4;i++){
      float v = acc[k][i];
      for (int off=32; off>0; off>>=1) v += __shfl_down(v, off);
      acc[k][i] = v;
    }
  }
  __shared__ float part[4][KK][4];
  int lane = t & 63, wv = t >> 6;
  if (lane == 0){
    #pragma unroll
    for (int k=0;k<KK;k++){ part[wv][k][0]=acc[k][0]; part[wv][k][1]=acc[k][1];
                            part[wv][k][2]=acc[k][2]; part[wv][k][3]=acc[k][3]; }
  }
  __syncthreads();
  if (t < 64){
    int k = t >> 2, i = t & 3;
    float s = part[0][k][i] + part[1][k][i] + part[2][k][i] + part[3][k][i];
    G[((size_t)b*KK + k)*CC + c0 + i] = s;
  }
}

// ---------------- K3: S = softmax_c(G) ; WS[b,o,k] = sum_c w_beta[o,c]*S[b,k,c] ----------------
__global__ __launch_bounds__(256) void k3_smws(
    const float* __restrict__ G, const float* __restrict__ w_beta, float* __restrict__ WSp)
{
  int b = blockIdx.x, t = threadIdx.x;
  __shared__ float sl[KK][CC];
  for (int k=0;k<KK;k++) sl[k][t] = G[((size_t)b*KK + k)*CC + t];
  __syncthreads();
  int lane = t & 63, wv = t >> 6;
  for (int r=0;r<4;r++){
    int k = wv*4 + r;
    float v0 = sl[k][lane], v1 = sl[k][lane+64], v2 = sl[k][lane+128], v3 = sl[k][lane+192];
    float m = fmaxf(fmaxf(v0,v1), fmaxf(v2,v3));
    for (int off=32; off>0; off>>=1) m = fmaxf(m, __shfl_xor(m, off));
    float e0=__expf(v0-m), e1=__expf(v1-m), e2=__expf(v2-m), e3=__expf(v3-m);
    float s = e0+e1+e2+e3;
    for (int off=32; off>0; off>>=1) s += __shfl_xor(s, off);
    float inv = 1.f/s;
    sl[k][lane]=e0*inv; sl[k][lane+64]=e1*inv; sl[k][lane+128]=e2*inv; sl[k][lane+192]=e3*inv;
  }
  __syncthreads();
  const float* wb = w_beta + (size_t)t*CC;
  float acc[KK];
  #pragma unroll
  for (int k=0;k<KK;k++) acc[k]=0.f;
  for (int c=0;c<CC;c++){
    float w = wb[c];
    #pragma unroll
    for (int k=0;k<KK;k++) acc[k] = fmaf(w, sl[k][c], acc[k]);
  }
  float* wsp = WSp + ((size_t)b*CC + t)*KK;
  #pragma unroll
  for (int k=0;k<KK;k++) wsp[k] = acc[k];
}

// ---------------- K4: out1[b,o,n] = sum_k WS[b,o,k]*F[b,k,n] + x[b,o,n]  -> bf16 ----------------
__global__ __launch_bounds__(256) void k4_out1(
    const float* __restrict__ F, const float* __restrict__ WSp,
    const float* __restrict__ x, u16* __restrict__ out1)
{
  __shared__ float ws[CC][KK];
  int t = threadIdx.x;
  int pid = blockIdx.x*256 + t;
  int b = pid / (NN/2);
  int n = (pid % (NN/2)) * 2;
  const float* wsg = WSp + (size_t)b*CC*KK;
  for (int i=t; i<CC*KK; i+=256) ws[i>>4][i&15] = wsg[i];
  __syncthreads();
  float f0[KK], f1[KK];
  const float* Fp = F + (size_t)b*KK*NN + n;
  #pragma unroll
  for (int k=0;k<KK;k++){
    float2 f2 = *reinterpret_cast<const float2*>(Fp + (size_t)k*NN);
    f0[k]=f2.x; f1[k]=f2.y;
  }
  const float* xp = x + (size_t)b*CC*NN + n;
  u16* op = out1 + (size_t)b*CC*NN + n;
  for (int o=0;o<CC;o++){
    float2 xv = *reinterpret_cast<const float2*>(xp + (size_t)o*NN);
    float v0 = xv.x, v1 = xv.y;
    const float* wr = ws[o];
    #pragma unroll
    for (int k=0;k<KK;k++){ v0 = fmaf(wr[k], f0[k], v0); v1 = fmaf(wr[k], f1[k], v1); }
    union { u16 h[2]; u32 u; } pk;
    pk.h[0] = f2us(v0); pk.h[1] = f2us(v1);
    *reinterpret_cast<u32*>(op + (size_t)o*NN) = pk.u;
  }
}

// ---------------- K5: spatial convs -> F4, Cm ----------------
__global__ __launch_bounds__(256) void k5_conv(
    const float* __restrict__ AM, const float* __restrict__ w1, const float* __restrict__ w3,
    const float* __restrict__ w5, const float* __restrict__ w7, const float* __restrict__ wf2c,
    float* __restrict__ F4, float* __restrict__ Cm)
{
  __shared__ float w3l[18], w5l[50], w7l[98], w1l[2], wcl[4];
  int t = threadIdx.x;
  if (t < 2)  w1l[t] = w1[t];
  if (t < 18) w3l[t] = w3[t];
  if (t < 50) w5l[t] = w5[t];
  if (t < 98) w7l[t] = w7[t];
  if (t < 4)  wcl[t] = wf2c[t];
  __syncthreads();
  int gid = blockIdx.x*256 + t;
  int b = gid / NN, n = gid % NN;
  int h = n / HW, w = n % HW;
  const float* am = AM + (size_t)b*2*NN;
  float a0 = am[n], a1 = am[NN + n];
  float s1v = lrelu(a0*w1l[0] + a1*w1l[1]);
  float s3v=0.f, s5v=0.f, s7v=0.f;
  for (int p=-3;p<=3;p++){
    int hh = h + p;
    if (hh < 0 || hh >= HW) continue;
    for (int q=-3;q<=3;q++){
      int ww = w + q;
      if (ww < 0 || ww >= HW) continue;
      float v0 = am[hh*HW+ww], v1 = am[NN + hh*HW + ww];
      s7v += v0*w7l[(p+3)*7 + (q+3)] + v1*w7l[49 + (p+3)*7 + (q+3)];
      if (p>=-2 && p<=2 && q>=-2 && q<=2)
        s5v += v0*w5l[(p+2)*5 + (q+2)] + v1*w5l[25 + (p+2)*5 + (q+2)];
      if (p>=-1 && p<=1 && q>=-1 && q<=1)
        s3v += v0*w3l[(p+1)*3 + (q+1)] + v1*w3l[9 + (p+1)*3 + (q+1)];
    }
  }
  s3v = lrelu(s3v); s5v = lrelu(s5v); s7v = lrelu(s7v);
  float* f4p = F4 + (size_t)b*4*NN + n;
  f4p[0] = s1v; f4p[NN] = s3v; f4p[2*(size_t)NN] = s5v; f4p[3*(size_t)NN] = s7v;
  Cm[(size_t)b*NN + n] = lrelu(s1v*wcl[0] + s3v*wcl[1] + s5v*wcl[2] + s7v*wcl[3]);
}

// ---------------- K6a: T[b,h,k] = sum_w Bm[b,h*96+w]*Cm[b,w*96+k] ----------------
__global__ __launch_bounds__(256) void k6a_t(
    const float* __restrict__ Bm, const float* __restrict__ Cm, float* __restrict__ Tsc)
{
  __shared__ float Cl[NN];
  int b = blockIdx.x, t = threadIdx.x;
  for (int i=t;i<NN;i+=256) Cl[i] = Cm[(size_t)b*NN + i];
  __syncthreads();
  const float* bp = Bm + (size_t)b*NN;
  for (int g=0; g<9; g++){
    int idx4 = (t + 256*g)*4;
    int h = idx4/96, k0 = idx4%96;
    float a0=0.f,a1=0.f,a2=0.f,a3=0.f;
    const float* brow = bp + h*96;
    for (int w2=0;w2<96;w2++){
      float bv = brow[w2];
      float4 cv = *reinterpret_cast<const float4*>(&Cl[w2*96 + k0]);
      a0=fmaf(bv,cv.x,a0); a1=fmaf(bv,cv.y,a1); a2=fmaf(bv,cv.z,a2); a3=fmaf(bv,cv.w,a3);
    }
    float4 o4; o4.x=a0; o4.y=a1; o4.z=a2; o4.w=a3;
    *reinterpret_cast<float4*>(Tsc + (size_t)b*NN + idx4) = o4;
  }
}

// ---------------- K6b: Ssp = softmax_k(T), stored bf16 ----------------
__global__ __launch_bounds__(256) void k6b_sm(
    const float* __restrict__ Tsc, u16* __restrict__ Ssp)
{
  int gid = blockIdx.x*256 + threadIdx.x;
  if (gid >= BN*96) return;
  int b = gid/96, h = gid%96;
  const float* row = Tsc + (size_t)b*NN + h*96;
  float m = -3e38f;
  for (int k=0;k<96;k++) m = fmaxf(m, row[k]);
  float s = 0.f;
  for (int k=0;k<96;k++) s += __expf(row[k]-m);
  float inv = 1.f/s;
  u16* orow = Ssp + (size_t)b*NN + h*96;
  for (int k=0;k<96;k++) orow[k] = f2us(__expf(row[k]-m)*inv);
}

// ---------------- K7: WD = w_e . lrelu(w_f2d . F4)   (48-pixel tile, 256 o) ----------------
__global__ __launch_bounds__(256) void k7_wd(
    const float* __restrict__ F4, const float* __restrict__ w_f2d,
    const float* __restrict__ w_e, u16* __restrict__ WD)
{
  __shared__ float f4l[4][48];
  __shared__ float Dl[CC][52];
  int t = threadIdx.x;
  int b = blockIdx.x / 192;
  int n0 = (blockIdx.x % 192) * 48;
  if (t < 192){
    int jj = t / 48, nof = t % 48;
    f4l[jj][nof] = F4[((size_t)b*4 + jj)*NN + n0 + nof];
  }
  __syncthreads();
  {
    float w0 = w_f2d[t*4+0], w1 = w_f2d[t*4+1];
    float w2 = w_f2d[t*4+2], w3 = w_f2d[t*4+3];
    #pragma unroll
    for (int j=0;j<48;j+=4){
      float4 d;
      d.x = lrelu(fmaf(w0,f4l[0][j+0], fmaf(w1,f4l[1][j+0], fmaf(w2,f4l[2][j+0], w3*f4l[3][j+0]))));
      d.y = lrelu(fmaf(w0,f4l[0][j+1], fmaf(w1,f4l[1][j+1], fmaf(w2,f4l[2][j+1], w3*f4l[3][j+1]))));
      d.z = lrelu(fmaf(w0,f4l[0][j+2], fmaf(w1,f4l[1][j+2], fmaf(w2,f4l[2][j+2], w3*f4l[3][j+2]))));
      d.w = lrelu(fmaf(w0,f4l[0][j+3], fmaf(w1,f4l[1][j+3], fmaf(w2,f4l[2][j+3], w3*f4l[3][j+3]))));
      *reinterpret_cast<float4*>(&Dl[t][j]) = d;
    }
  }
  __syncthreads();
  float acc[48];
  #pragma unroll
  for (int j=0;j<48;j++) acc[j]=0.f;
  const float* wep = w_e + (size_t)t*CC;
  for (int c=0;c<CC;c++){
    float wv = wep[c];
    const float* dp = Dl[c];
    #pragma unroll
    for (int j=0;j<48;j+=4){
      float4 dv = *reinterpret_cast<const float4*>(dp + j);
      acc[j+0]=fmaf(wv,dv.x,acc[j+0]); acc[j+1]=fmaf(wv,dv.y,acc[j+1]);
      acc[j+2]=fmaf(wv,dv.z,acc[j+2]); acc[j+3]=fmaf(wv,dv.w,acc[j+3]);
    }
  }
  u16* wdp = WD + ((size_t)b*CC + t)*NN + n0;
  #pragma unroll
  for (int j=0;j<48;j+=8){
    union { u16 h[8]; uint4 u; } pk;
    #pragma unroll
    for (int e=0;e<8;e++) pk.h[e] = f2us(acc[j+e]);
    *reinterpret_cast<uint4*>(wdp + j) = pk.u;
  }
}

// ---------------- K8: out2[b,o] = Ssp_b (96x96) x WD[b,o] (96x96) + x  -> bf16 ----------------
__global__ __launch_bounds__(256) void k8_out2(
    const u16* __restrict__ Ssp, const u16* __restrict__ WD,
    const float* __restrict__ x, u16* __restrict__ out2)
{
  __shared__ u16 Sl[NN];
  __shared__ float Wl[NN];
  int t = threadIdx.x;
  int b = blockIdx.x >> 8, o = blockIdx.x & 255;
  const u32* sp = reinterpret_cast<const u32*>(Ssp + (size_t)b*NN);
  const u32* wp = reinterpret_cast<const u32*>(WD + ((size_t)b*CC + o)*NN);
  u32* sl32 = reinterpret_cast<u32*>(Sl);
  for (int i=t; i<NN/2; i+=256){
    sl32[i] = sp[i];
    u32 wv = wp[i];
    Wl[2*i]   = us2f((u16)(wv & 0xffffu));
    Wl[2*i+1] = us2f((u16)(wv >> 16));
  }
  __syncthreads();
  const float* xp = x + ((size_t)b*CC + o)*NN;
  u16* op = out2 + ((size_t)b*CC + o)*NN;
  for (int g=0; g<9; g++){
    int idx4 = (t + 256*g)*4;
    int h = idx4/96, w0 = idx4%96;
    float a0=0.f,a1=0.f,a2=0.f,a3=0.f;
    const u16* srow = &Sl[h*96];
    for (int kk=0;kk<96;kk++){
      float sv = us2f(srow[kk]);
      float4 wv4 = *reinterpret_cast<const float4*>(&Wl[kk*96 + w0]);
      a0=fmaf(sv,wv4.x,a0); a1=fmaf(sv,wv4.y,a1); a2=fmaf(sv,wv4.z,a2); a3=fmaf(sv,wv4.w,a3);
    }
    float4 xr = *reinterpret_cast<const float4*>(xp + idx4);
    a0 += xr.x; a1 += xr.y; a2 += xr.z; a3 += xr.w;
    union { u16 h4[4]; uint2 u; } pk;
    pk.h4[0]=f2us(a0); pk.h4[1]=f2us(a1); pk.h4[2]=f2us(a2); pk.h4[3]=f2us(a3);
    *reinterpret_cast<uint2*>(op + idx4) = pk.u;
  }
}

#define GEMM16_BLOCK(wbase)                                            \
  do {                                                                 \
    float wv[16];                                                      \
    _Pragma("unroll")                                                  \
    for (int q=0;q<16;q++) wv[q] = (wbase)[q];                         \
    _Pragma("unroll")                                                  \
    for (int q=0;q<16;q++){                                            \
      const float* ip = in_l[q];                                       \
      _Pragma("unroll")                                                \
      for (int j=0;j<48;j+=4){                                         \
        float4 v = *reinterpret_cast<const float4*>(ip + j);           \
        acc[j+0]=fmaf(wv[q],v.x,acc[j+0]); acc[j+1]=fmaf(wv[q],v.y,acc[j+1]); \
        acc[j+2]=fmaf(wv[q],v.z,acc[j+2]); acc[j+3]=fmaf(wv[q],v.w,acc[j+3]); \
      }                                                                \
    }                                                                  \
  } while(0)

// ---------------- K9: Hh = lrelu(w_h.[out1,out2])  (bf16 in, bf16 out) ----------------
__global__ __launch_bounds__(256) void k9_hh(
    const u16* __restrict__ out1, const u16* __restrict__ out2,
    const float* __restrict__ w_h, u16* __restrict__ Hh)
{
  __shared__ float in_l[16][48];
  int t = threadIdx.x;
  int b = blockIdx.x / 192;
  int n0 = (blockIdx.x % 192) * 48;
  float acc[48];
  #pragma unroll
  for (int j=0;j<48;j++) acc[j]=0.f;
  const float* wp = w_h + (size_t)t*512;
  int cc = t >> 4, j3 = (t & 15)*3;
  for (int half=0; half<2; half++){
    const u16* src = half ? out2 : out1;
    const float* wph = wp + half*256;
    for (int c0=0; c0<CC; c0+=16){
      __syncthreads();
      const u16* sp = src + ((size_t)b*CC + c0 + cc)*NN + n0 + j3;
      in_l[cc][j3+0] = us2f(sp[0]);
      in_l[cc][j3+1] = us2f(sp[1]);
      in_l[cc][j3+2] = us2f(sp[2]);
      __syncthreads();
      GEMM16_BLOCK(wph + c0);
    }
  }
  u16* hp = Hh + ((size_t)b*CC + t)*NN + n0;
  #pragma unroll
  for (int j=0;j<48;j+=8){
    union { u16 h[8]; uint4 u; } pk;
    #pragma unroll
    for (int e=0;e<8;e++) pk.h[e] = f2us(lrelu(acc[j+e]));
    *reinterpret_cast<uint4*>(hp + j) = pk.u;
  }
}

// ---------------- K10: M = sigmoid(w_m.[Hh,x]) ; out = lrelu(w_hm.[Hh,M])  -> fp32 ----------------
__global__ __launch_bounds__(256) void k10_final(
    const u16* __restrict__ Hh, const float* __restrict__ x,
    const float* __restrict__ w_m, const float* __restrict__ w_hm,
    float* __restrict__ out)
{
  __shared__ float in_l[16][48];
  __shared__ float Mt[CC][52];
  int t = threadIdx.x;
  int b = blockIdx.x / 192;
  int n0 = (blockIdx.x % 192) * 48;
  int cc = t >> 4, j3 = (t & 15)*3;
  float acc[48];
  #pragma unroll
  for (int j=0;j<48;j++) acc[j]=0.f;
  const float* wmp = w_m + (size_t)t*512;
  // phase A: M — half 0: Hh (bf16)
  for (int c0=0; c0<CC; c0+=16){
    __syncthreads();
    const u16* sp = Hh + ((size_t)b*CC + c0 + cc)*NN + n0 + j3;
    in_l[cc][j3+0]=us2f(sp[0]); in_l[cc][j3+1]=us2f(sp[1]); in_l[cc][j3+2]=us2f(sp[2]);
    __syncthreads();
    GEMM16_BLOCK(wmp + c0);
  }
  // phase A: M — half 1: x (fp32)
  for (int c0=0; c0<CC; c0+=16){
    __syncthreads();
    const float* sp = x + ((size_t)b*CC + c0 + cc)*NN + n0 + j3;
    in_l[cc][j3+0]=sp[0]; in_l[cc][j3+1]=sp[1]; in_l[cc][j3+2]=sp[2];
    __syncthreads();
    GEMM16_BLOCK(wmp + 256 + c0);
  }
  #pragma unroll
  for (int j=0;j<48;j++) Mt[t][j] = 1.f/(1.f + __expf(-acc[j]));
  __syncthreads();
  // phase B: H_M
  #pragma unroll
  for (int j=0;j<48;j++) acc[j]=0.f;
  const float* whp = w_hm + (size_t)t*512;
  for (int c0=0; c0<CC; c0+=16){
    __syncthreads();
    const u16* sp = Hh + ((size_t)b*CC + c0 + cc)*NN + n0 + j3;
    in_l[cc][j3+0]=us2f(sp[0]); in_l[cc][j3+1]=us2f(sp[1]); in_l[cc][j3+2]=us2f(sp[2]);
    __syncthreads();
    GEMM16_BLOCK(whp + c0);
  }
  for (int c=0;c<CC;c++){
    float wv = whp[256+c];
    const float* mp = Mt[c];
    #pragma unroll
    for (int j=0;j<48;j+=4){
      float4 v = *reinterpret_cast<const float4*>(mp + j);
      acc[j+0]=fmaf(wv,v.x,acc[j+0]); acc[j+1]=fmaf(wv,v.y,acc[j+1]);
      acc[j+2]=fmaf(wv,v.z,acc[j+2]); acc[j+3]=fmaf(wv,v.w,acc[j+3]);
    }
  }
  float* op = out + ((size_t)b*CC + t)*NN + n0;
  #pragma unroll
  for (int j=0;j<48;j+=4){
    float4 o4;
    o4.x = lrelu(acc[j+0]); o4.y = lrelu(acc[j+1]);
    o4.z = lrelu(acc[j+2]); o4.w = lrelu(acc[j+3]);
    *reinterpret_cast<float4*>(op + j) = o4;
  }
}

extern "C" void kernel_launch(void* const* d_in, const int* in_sizes, int n_in,
                              void* d_out, int out_size, void* d_ws, size_t ws_size,
                              hipStream_t stream)
{
  const float* x     = (const float*)d_in[0];
  const float* w_f   = (const float*)d_in[1];
  const float* w_beta= (const float*)d_in[2];
  const float* w1    = (const float*)d_in[3];
  const float* w3    = (const float*)d_in[4];
  const float* w5    = (const float*)d_in[5];
  const float* w7    = (const float*)d_in[6];
  const float* w_a2b = (const float*)d_in[7];
  const float* w_f2c = (const float*)d_in[8];
  const float* w_f2d = (const float*)d_in[9];
  const float* w_e   = (const float*)d_in[10];
  const float* w_h   = (const float*)d_in[11];
  const float* w_m   = (const float*)d_in[12];
  const float* w_hm  = (const float*)d_in[13];

  char* ws = (char*)d_ws;
  size_t off = 0;
  auto alloc = [&](size_t bytes) -> void* {
    void* p = ws + off; off += (bytes + 255) & ~(size_t)255; return p;
  };
  float* F    = (float*)alloc(sizeof(float)*(size_t)BN*KK*NN);
  float* AMb  = (float*)alloc(sizeof(float)*(size_t)BN*2*NN);
  float* Bmv  = (float*)alloc(sizeof(float)*(size_t)BN*NN);
  float* Cmv  = (float*)alloc(sizeof(float)*(size_t)BN*NN);
  float* F4   = (float*)alloc(sizeof(float)*(size_t)BN*4*NN);
  float* G    = (float*)alloc(sizeof(float)*(size_t)BN*KK*CC);
  float* WSp  = (float*)alloc(sizeof(float)*(size_t)BN*CC*KK);
  float* Tsc  = (float*)alloc(sizeof(float)*(size_t)BN*NN);
  u16*   Ssp  = (u16*)alloc(sizeof(u16)*(size_t)BN*NN);
  u16*   WD   = (u16*)alloc(sizeof(u16)*(size_t)BN*CC*NN);
  u16*   o1   = (u16*)alloc(sizeof(u16)*(size_t)BN*CC*NN);
  u16*   o2   = (u16*)alloc(sizeof(u16)*(size_t)BN*CC*NN);
  u16*   Hh   = (u16*)alloc(sizeof(u16)*(size_t)BN*CC*NN);
  (void)ws_size; (void)in_sizes; (void)n_in; (void)out_size;

  k1_fx   <<<144, 256, 0, stream>>>(x, w_f, w_a2b, F, AMb, Bmv);
  k2_g    <<<512, 256, 0, stream>>>(x, F, G);
  k3_smws <<<8,   256, 0, stream>>>(G, w_beta, WSp);
  k4_out1 <<<144, 256, 0, stream>>>(F, WSp, x, o1);
  k5_conv <<<288, 256, 0, stream>>>(AMb, w1, w3, w5, w7, w_f2c, F4, Cmv);
  k6a_t   <<<8,   256, 0, stream>>>(Bmv, Cmv, Tsc);
  k6b_sm  <<<3,   256, 0, stream>>>(Tsc, Ssp);
  k7_wd   <<<1536,256, 0, stream>>>(F4, w_f2d, w_e, WD);
  k8_out2 <<<2048,256, 0, stream>>>(Ssp, WD, x, o2);
  k9_hh   <<<1536,256, 0, stream>>>(o1, o2, w_h, Hh);
  k10_final<<<1536,256,0, stream>>>(Hh, x, w_m, w_hm, (float*)d_out);
}

// Round 4
// 885.046 us; speedup vs baseline: 2.3404x; 2.3404x over previous
//
#include <hip/hip_runtime.h>

typedef unsigned short u16;
typedef unsigned int   u32;

#define BN 8
#define CC 256
#define HW 96
#define NN 9216   // 96*96
#define KK 16

typedef __attribute__((ext_vector_type(8))) short bf16x8;
typedef __attribute__((ext_vector_type(4))) float f32x4;

__device__ __forceinline__ float us2f(u16 u){
  union { u32 i; float f; } v; v.i = ((u32)u) << 16; return v.f;
}
__device__ __forceinline__ u16 f2us(float f){
  union { float f; u32 i; } v; v.f = f;
  u32 x = v.i;
  u32 r = (x + 0x7fffu + ((x >> 16) & 1u)) >> 16;  // RNE
  return (u16)r;
}
__device__ __forceinline__ float lrelu(float v){ return v >= 0.f ? v : 0.001f*v; }

// LDS swizzle for [32 n][512 c] bf16 tile: 16B-slot XOR keeps b128 reads aligned.
__device__ __forceinline__ u32 swz(int n, int c){
  return (u32)(n*1024 + ((((c>>3) ^ (n&31)) & 63)<<4) + ((c&7)<<1));
}

// ---------------- K1: F = w_f.x ; Bm = lrelu(w_a2b.x) ; AM = [mean_c, max_c] ----------------
__global__ __launch_bounds__(256) void k1_fx(
    const float* __restrict__ x, const float* __restrict__ w_f, const float* __restrict__ w_a2b,
    float* __restrict__ F, float* __restrict__ AM, float* __restrict__ Bm)
{
  __shared__ float wf[CC][KK];   // [c][k]
  __shared__ float wa[CC];
  int t = threadIdx.x;
  for (int i = t; i < KK*CC; i += 256) wf[i & 255][i >> 8] = w_f[i];
  wa[t] = w_a2b[t];
  __syncthreads();
  int pid = blockIdx.x*256 + t;             // 2 pixels per thread
  int b = pid / (NN/2);
  int n = (pid % (NN/2)) * 2;
  const float* xp = x + (size_t)b*CC*NN + n;
  float a0[KK], a1[KK];
  #pragma unroll
  for (int k=0;k<KK;k++){ a0[k]=0.f; a1[k]=0.f; }
  float s0=0.f,s1=0.f,m0=-3e38f,m1=-3e38f,b0=0.f,b1=0.f;
  for (int c=0;c<CC;c++){
    float2 xv = *reinterpret_cast<const float2*>(xp + (size_t)c*NN);
    float v0 = xv.x, v1 = xv.y;
    s0 += v0; s1 += v1;
    m0 = fmaxf(m0, v0); m1 = fmaxf(m1, v1);
    b0 = fmaf(wa[c], v0, b0); b1 = fmaf(wa[c], v1, b1);
    const float* wr = wf[c];
    #pragma unroll
    for (int k=0;k<KK;k++){ a0[k] = fmaf(wr[k], v0, a0[k]); a1[k] = fmaf(wr[k], v1, a1[k]); }
  }
  float* Fp = F + (size_t)b*KK*NN + n;
  #pragma unroll
  for (int k=0;k<KK;k++){ float2 f2; f2.x=a0[k]; f2.y=a1[k];
    *reinterpret_cast<float2*>(Fp + (size_t)k*NN) = f2; }
  float2 av; av.x = s0*(1.f/256.f); av.y = s1*(1.f/256.f);
  float2 mx; mx.x = m0; mx.y = m1;
  *reinterpret_cast<float2*>(AM + (size_t)b*2*NN + n) = av;
  *reinterpret_cast<float2*>(AM + (size_t)b*2*NN + NN + n) = mx;
  float2 bm; bm.x = lrelu(b0); bm.y = lrelu(b1);
  *reinterpret_cast<float2*>(Bm + (size_t)b*NN + n) = bm;
}

// ---------------- K2: G[b,k,c] = sum_n F[b,k,n]*x[b,c,n]  (4 c per block) ----------------
__global__ __launch_bounds__(256) void k2_g(
    const float* __restrict__ x, const float* __restrict__ F, float* __restrict__ G)
{
  int b = blockIdx.x >> 6;
  int c0 = (blockIdx.x & 63) * 4;
  int t = threadIdx.x;
  const float* Fp = F + (size_t)b*KK*NN;
  const float* xp = x + ((size_t)b*CC + c0)*NN;
  float acc[KK][4];
  #pragma unroll
  for (int k=0;k<KK;k++){ acc[k][0]=acc[k][1]=acc[k][2]=acc[k][3]=0.f; }
  for (int n = t; n < NN; n += 256){
    float xv0 = xp[n];
    float xv1 = xp[(size_t)NN + n];
    float xv2 = xp[(size_t)2*NN + n];
    float xv3 = xp[(size_t)3*NN + n];
    #pragma unroll
    for (int k=0;k<KK;k++){
      float fv = Fp[(size_t)k*NN + n];
      acc[k][0] = fmaf(fv, xv0, acc[k][0]);
      acc[k][1] = fmaf(fv, xv1, acc[k][1]);
      acc[k][2] = fmaf(fv, xv2, acc[k][2]);
      acc[k][3] = fmaf(fv, xv3, acc[k][3]);
    }
  }
  #pragma unroll
  for (int k=0;k<KK;k++){
    #pragma unroll
    for (int i=0;i<4;i++){
      float v = acc[k][i];
      for (int off=32; off>0; off>>=1) v += __shfl_down(v, off);
      acc[k][i] = v;
    }
  }
  __shared__ float part[4][KK][4];
  int lane = t & 63, wv = t >> 6;
  if (lane == 0){
    #pragma unroll
    for (int k=0;k<KK;k++){ part[wv][k][0]=acc[k][0]; part[wv][k][1]=acc[k][1];
                            part[wv][k][2]=acc[k][2]; part[wv][k][3]=acc[k][3]; }
  }
  __syncthreads();
  if (t < 64){
    int k = t >> 2, i = t & 3;
    float s = part[0][k][i] + part[1][k][i] + part[2][k][i] + part[3][k][i];
    G[((size_t)b*KK + k)*CC + c0 + i] = s;
  }
}

// ---------------- K3: S = softmax_c(G) ; WS[b,o,k] = sum_c w_beta[o,c]*S[b,k,c] ----------------
__global__ __launch_bounds__(256) void k3_smws(
    const float* __restrict__ G, const float* __restrict__ w_beta, float* __restrict__ WSp)
{
  int b = blockIdx.x, t = threadIdx.x;
  __shared__ float sl[KK][CC];
  for (int k=0;k<KK;k++) sl[k][t] = G[((size_t)b*KK + k)*CC + t];
  __syncthreads();
  int lane = t & 63, wv = t >> 6;
  for (int r=0;r<4;r++){
    int k = wv*4 + r;
    float v0 = sl[k][lane], v1 = sl[k][lane+64], v2 = sl[k][lane+128], v3 = sl[k][lane+192];
    float m = fmaxf(fmaxf(v0,v1), fmaxf(v2,v3));
    for (int off=32; off>0; off>>=1) m = fmaxf(m, __shfl_xor(m, off));
    float e0=__expf(v0-m), e1=__expf(v1-m), e2=__expf(v2-m), e3=__expf(v3-m);
    float s = e0+e1+e2+e3;
    for (int off=32; off>0; off>>=1) s += __shfl_xor(s, off);
    float inv = 1.f/s;
    sl[k][lane]=e0*inv; sl[k][lane+64]=e1*inv; sl[k][lane+128]=e2*inv; sl[k][lane+192]=e3*inv;
  }
  __syncthreads();
  const float* wb = w_beta + (size_t)t*CC;
  float acc[KK];
  #pragma unroll
  for (int k=0;k<KK;k++) acc[k]=0.f;
  for (int c=0;c<CC;c++){
    float w = wb[c];
    #pragma unroll
    for (int k=0;k<KK;k++) acc[k] = fmaf(w, sl[k][c], acc[k]);
  }
  float* wsp = WSp + ((size_t)b*CC + t)*KK;
  #pragma unroll
  for (int k=0;k<KK;k++) wsp[k] = acc[k];
}

// ---------------- K4: out1[b,o,n] = sum_k WS[b,o,k]*F[b,k,n] + x[b,o,n]  -> bf16 ----------------
__global__ __launch_bounds__(256) void k4_out1(
    const float* __restrict__ F, const float* __restrict__ WSp,
    const float* __restrict__ x, u16* __restrict__ out1)
{
  __shared__ float ws[CC][KK];
  int t = threadIdx.x;
  int pid = blockIdx.x*256 + t;
  int b = pid / (NN/2);
  int n = (pid % (NN/2)) * 2;
  const float* wsg = WSp + (size_t)b*CC*KK;
  for (int i=t; i<CC*KK; i+=256) ws[i>>4][i&15] = wsg[i];
  __syncthreads();
  float f0[KK], f1[KK];
  const float* Fp = F + (size_t)b*KK*NN + n;
  #pragma unroll
  for (int k=0;k<KK;k++){
    float2 f2 = *reinterpret_cast<const float2*>(Fp + (size_t)k*NN);
    f0[k]=f2.x; f1[k]=f2.y;
  }
  const float* xp = x + (size_t)b*CC*NN + n;
  u16* op = out1 + (size_t)b*CC*NN + n;
  for (int o=0;o<CC;o++){
    float2 xv = *reinterpret_cast<const float2*>(xp + (size_t)o*NN);
    float v0 = xv.x, v1 = xv.y;
    const float* wr = ws[o];
    #pragma unroll
    for (int k=0;k<KK;k++){ v0 = fmaf(wr[k], f0[k], v0); v1 = fmaf(wr[k], f1[k], v1); }
    union { u16 h[2]; u32 u; } pk;
    pk.h[0] = f2us(v0); pk.h[1] = f2us(v1);
    *reinterpret_cast<u32*>(op + (size_t)o*NN) = pk.u;
  }
}

// ---------------- K5: spatial convs -> F4, Cm ----------------
__global__ __launch_bounds__(256) void k5_conv(
    const float* __restrict__ AM, const float* __restrict__ w1, const float* __restrict__ w3,
    const float* __restrict__ w5, const float* __restrict__ w7, const float* __restrict__ wf2c,
    float* __restrict__ F4, float* __restrict__ Cm)
{
  __shared__ float w3l[18], w5l[50], w7l[98], w1l[2], wcl[4];
  int t = threadIdx.x;
  if (t < 2)  w1l[t] = w1[t];
  if (t < 18) w3l[t] = w3[t];
  if (t < 50) w5l[t] = w5[t];
  if (t < 98) w7l[t] = w7[t];
  if (t < 4)  wcl[t] = wf2c[t];
  __syncthreads();
  int gid = blockIdx.x*256 + t;
  int b = gid / NN, n = gid % NN;
  int h = n / HW, w = n % HW;
  const float* am = AM + (size_t)b*2*NN;
  float a0 = am[n], a1 = am[NN + n];
  float s1v = lrelu(a0*w1l[0] + a1*w1l[1]);
  float s3v=0.f, s5v=0.f, s7v=0.f;
  for (int p=-3;p<=3;p++){
    int hh = h + p;
    if (hh < 0 || hh >= HW) continue;
    for (int q=-3;q<=3;q++){
      int ww = w + q;
      if (ww < 0 || ww >= HW) continue;
      float v0 = am[hh*HW+ww], v1 = am[NN + hh*HW + ww];
      s7v += v0*w7l[(p+3)*7 + (q+3)] + v1*w7l[49 + (p+3)*7 + (q+3)];
      if (p>=-2 && p<=2 && q>=-2 && q<=2)
        s5v += v0*w5l[(p+2)*5 + (q+2)] + v1*w5l[25 + (p+2)*5 + (q+2)];
      if (p>=-1 && p<=1 && q>=-1 && q<=1)
        s3v += v0*w3l[(p+1)*3 + (q+1)] + v1*w3l[9 + (p+1)*3 + (q+1)];
    }
  }
  s3v = lrelu(s3v); s5v = lrelu(s5v); s7v = lrelu(s7v);
  float* f4p = F4 + (size_t)b*4*NN + n;
  f4p[0] = s1v; f4p[NN] = s3v; f4p[2*(size_t)NN] = s5v; f4p[3*(size_t)NN] = s7v;
  Cm[(size_t)b*NN + n] = lrelu(s1v*wcl[0] + s3v*wcl[1] + s5v*wcl[2] + s7v*wcl[3]);
}

// ---------------- K6a: T[b,h,k] = sum_w Bm[b,h*96+w]*Cm[b,w*96+k] ----------------
__global__ __launch_bounds__(256) void k6a_t(
    const float* __restrict__ Bm, const float* __restrict__ Cm, float* __restrict__ Tsc)
{
  __shared__ float Cl[NN];
  int b = blockIdx.x, t = threadIdx.x;
  for (int i=t;i<NN;i+=256) Cl[i] = Cm[(size_t)b*NN + i];
  __syncthreads();
  const float* bp = Bm + (size_t)b*NN;
  for (int g=0; g<9; g++){
    int idx4 = (t + 256*g)*4;
    int h = idx4/96, k0 = idx4%96;
    float a0=0.f,a1=0.f,a2=0.f,a3=0.f;
    const float* brow = bp + h*96;
    for (int w2=0;w2<96;w2++){
      float bv = brow[w2];
      float4 cv = *reinterpret_cast<const float4*>(&Cl[w2*96 + k0]);
      a0=fmaf(bv,cv.x,a0); a1=fmaf(bv,cv.y,a1); a2=fmaf(bv,cv.z,a2); a3=fmaf(bv,cv.w,a3);
    }
    float4 o4; o4.x=a0; o4.y=a1; o4.z=a2; o4.w=a3;
    *reinterpret_cast<float4*>(Tsc + (size_t)b*NN + idx4) = o4;
  }
}

// ---------------- K6b: Ssp = softmax_k(T), stored bf16 ----------------
__global__ __launch_bounds__(256) void k6b_sm(
    const float* __restrict__ Tsc, u16* __restrict__ Ssp)
{
  int gid = blockIdx.x*256 + threadIdx.x;
  if (gid >= BN*96) return;
  int b = gid/96, h = gid%96;
  const float* row = Tsc + (size_t)b*NN + h*96;
  float m = -3e38f;
  for (int k=0;k<96;k++) m = fmaxf(m, row[k]);
  float s = 0.f;
  for (int k=0;k<96;k++) s += __expf(row[k]-m);
  float inv = 1.f/s;
  u16* orow = Ssp + (size_t)b*NN + h*96;
  for (int k=0;k<96;k++) orow[k] = f2us(__expf(row[k]-m)*inv);
}

// ---------------- K7: WD = w_e . lrelu(w_f2d . F4)   (48-pixel tile, 256 o) ----------------
__global__ __launch_bounds__(256) void k7_wd(
    const float* __restrict__ F4, const float* __restrict__ w_f2d,
    const float* __restrict__ w_e, u16* __restrict__ WD)
{
  __shared__ float f4l[4][48];
  __shared__ float Dl[CC][52];
  int t = threadIdx.x;
  int b = blockIdx.x / 192;
  int n0 = (blockIdx.x % 192) * 48;
  if (t < 192){
    int jj = t / 48, nof = t % 48;
    f4l[jj][nof] = F4[((size_t)b*4 + jj)*NN + n0 + nof];
  }
  __syncthreads();
  {
    float w0 = w_f2d[t*4+0], w1 = w_f2d[t*4+1];
    float w2 = w_f2d[t*4+2], w3 = w_f2d[t*4+3];
    #pragma unroll
    for (int j=0;j<48;j+=4){
      float4 d;
      d.x = lrelu(fmaf(w0,f4l[0][j+0], fmaf(w1,f4l[1][j+0], fmaf(w2,f4l[2][j+0], w3*f4l[3][j+0]))));
      d.y = lrelu(fmaf(w0,f4l[0][j+1], fmaf(w1,f4l[1][j+1], fmaf(w2,f4l[2][j+1], w3*f4l[3][j+1]))));
      d.z = lrelu(fmaf(w0,f4l[0][j+2], fmaf(w1,f4l[1][j+2], fmaf(w2,f4l[2][j+2], w3*f4l[3][j+2]))));
      d.w = lrelu(fmaf(w0,f4l[0][j+3], fmaf(w1,f4l[1][j+3], fmaf(w2,f4l[2][j+3], w3*f4l[3][j+3]))));
      *reinterpret_cast<float4*>(&Dl[t][j]) = d;
    }
  }
  __syncthreads();
  float acc[48];
  #pragma unroll
  for (int j=0;j<48;j++) acc[j]=0.f;
  const float* wep = w_e + (size_t)t*CC;
  for (int c=0;c<CC;c++){
    float wv = wep[c];
    const float* dp = Dl[c];
    #pragma unroll
    for (int j=0;j<48;j+=4){
      float4 dv = *reinterpret_cast<const float4*>(dp + j);
      acc[j+0]=fmaf(wv,dv.x,acc[j+0]); acc[j+1]=fmaf(wv,dv.y,acc[j+1]);
      acc[j+2]=fmaf(wv,dv.z,acc[j+2]); acc[j+3]=fmaf(wv,dv.w,acc[j+3]);
    }
  }
  u16* wdp = WD + ((size_t)b*CC + t)*NN + n0;
  #pragma unroll
  for (int j=0;j<48;j+=8){
    union { u16 h[8]; uint4 u; } pk;
    #pragma unroll
    for (int e=0;e<8;e++) pk.h[e] = f2us(acc[j+e]);
    *reinterpret_cast<uint4*>(wdp + j) = pk.u;
  }
}

// ---------------- K8: out2[b,o] = Ssp_b (96x96) x WD[b,o] (96x96) + x  -> bf16 ----------------
__global__ __launch_bounds__(256) void k8_out2(
    const u16* __restrict__ Ssp, const u16* __restrict__ WD,
    const float* __restrict__ x, u16* __restrict__ out2)
{
  __shared__ u16 Sl[NN];
  __shared__ float Wl[NN];
  int t = threadIdx.x;
  int b = blockIdx.x >> 8, o = blockIdx.x & 255;
  const u32* sp = reinterpret_cast<const u32*>(Ssp + (size_t)b*NN);
  const u32* wp = reinterpret_cast<const u32*>(WD + ((size_t)b*CC + o)*NN);
  u32* sl32 = reinterpret_cast<u32*>(Sl);
  for (int i=t; i<NN/2; i+=256){
    sl32[i] = sp[i];
    u32 wv = wp[i];
    Wl[2*i]   = us2f((u16)(wv & 0xffffu));
    Wl[2*i+1] = us2f((u16)(wv >> 16));
  }
  __syncthreads();
  const float* xp = x + ((size_t)b*CC + o)*NN;
  u16* op = out2 + ((size_t)b*CC + o)*NN;
  for (int g=0; g<9; g++){
    int idx4 = (t + 256*g)*4;
    int h = idx4/96, w0 = idx4%96;
    float a0=0.f,a1=0.f,a2=0.f,a3=0.f;
    const u16* srow = &Sl[h*96];
    for (int kk=0;kk<96;kk++){
      float sv = us2f(srow[kk]);
      float4 wv4 = *reinterpret_cast<const float4*>(&Wl[kk*96 + w0]);
      a0=fmaf(sv,wv4.x,a0); a1=fmaf(sv,wv4.y,a1); a2=fmaf(sv,wv4.z,a2); a3=fmaf(sv,wv4.w,a3);
    }
    float4 xr = *reinterpret_cast<const float4*>(xp + idx4);
    a0 += xr.x; a1 += xr.y; a2 += xr.z; a3 += xr.w;
    union { u16 h4[4]; uint2 u; } pk;
    pk.h4[0]=f2us(a0); pk.h4[1]=f2us(a1); pk.h4[2]=f2us(a2); pk.h4[3]=f2us(a3);
    *reinterpret_cast<uint2*>(op + idx4) = pk.u;
  }
}

// ---------------- KW: pack w_h / w_m / w_hm (256x512 fp32) into bf16 MFMA A-frag order ----------------
// wpk[mat][ot][ks][lane][e] = W[ot*16 + (lane&15)][ks*32 + (lane>>4)*8 + e]
__global__ __launch_bounds__(256) void kw_pack(
    const float* __restrict__ w_h, const float* __restrict__ w_m,
    const float* __restrict__ w_hm, u16* __restrict__ wpk)
{
  int gid = blockIdx.x*256 + threadIdx.x;   // 49152
  int mat = gid >> 14;
  int r = gid & 16383;
  int ot = r >> 10;
  int ks = (r >> 6) & 15;
  int l  = r & 63;
  const float* W = (mat==0) ? w_h : ((mat==1) ? w_m : w_hm);
  int o = ot*16 + (l & 15);
  int c = ks*32 + (l >> 4)*8;
  const float* src = W + (size_t)o*512 + c;
  union { u16 h[8]; uint4 u; } pk;
  #pragma unroll
  for (int e=0;e<8;e++) pk.h[e] = f2us(src[e]);
  *reinterpret_cast<uint4*>(wpk + (size_t)gid*8) = pk.u;
}

// ---------------- K9M: Hh = lrelu(w_h.[out1,out2])  — MFMA ----------------
__global__ __launch_bounds__(256) void k9m(
    const u16* __restrict__ o1, const u16* __restrict__ o2,
    const u16* __restrict__ wpk, u16* __restrict__ Hh)
{
  __shared__ uint4 sm4[2048];                 // 32 KB: [32 n][512 c] bf16, swizzled
  char* sm = reinterpret_cast<char*>(sm4);
  int t = threadIdx.x;
  int b = blockIdx.x / 288;
  int n0 = (blockIdx.x % 288) * 32;
  // stage In^T: c 0..255 = out1, 256..511 = out2
  for (int it=0; it<8; ++it){
    int s = it*256 + t;
    int c = s >> 2, q = s & 3;
    const u16* src = (c < 256) ? (o1 + ((size_t)b*CC + c)*NN)
                               : (o2 + ((size_t)b*CC + (c-256))*NN);
    union { u16 h[8]; uint4 u; } v;
    v.u = *reinterpret_cast<const uint4*>(src + n0 + q*8);
    #pragma unroll
    for (int e=0;e<8;e++)
      *reinterpret_cast<u16*>(sm + swz(q*8+e, c)) = v.h[e];
  }
  __syncthreads();
  int w = t >> 6, l = t & 63, ln = l & 15, lk = l >> 4;
  f32x4 acc[4][2];
  #pragma unroll
  for (int i=0;i<4;i++){ acc[i][0] = 0.f; acc[i][1] = 0.f; }
  for (int ks=0; ks<16; ++ks){
    bf16x8 bfr0 = *reinterpret_cast<const bf16x8*>(sm + swz(ln,    ks*32 + lk*8));
    bf16x8 bfr1 = *reinterpret_cast<const bf16x8*>(sm + swz(16+ln, ks*32 + lk*8));
    #pragma unroll
    for (int mf=0; mf<4; mf++){
      int ot = w*4 + mf;
      bf16x8 afr = *reinterpret_cast<const bf16x8*>(wpk + ((size_t)(ot*16 + ks)*64 + l)*8);
      acc[mf][0] = __builtin_amdgcn_mfma_f32_16x16x32_bf16(afr, bfr0, acc[mf][0], 0,0,0);
      acc[mf][1] = __builtin_amdgcn_mfma_f32_16x16x32_bf16(afr, bfr1, acc[mf][1], 0,0,0);
    }
  }
  #pragma unroll
  for (int mf=0; mf<4; mf++){
    #pragma unroll
    for (int nf=0; nf<2; nf++){
      #pragma unroll
      for (int r=0;r<4;r++){
        int o = w*64 + mf*16 + lk*4 + r;
        Hh[((size_t)b*CC + o)*NN + n0 + nf*16 + ln] = f2us(lrelu(acc[mf][nf][r]));
      }
    }
  }
}

// ---------------- K10M: M = sigmoid(w_m.[Hh,x]); out = lrelu(w_hm.[Hh,M]) — MFMA, fp32 out ----------------
__global__ __launch_bounds__(256) void k10m(
    const u16* __restrict__ Hh, const float* __restrict__ x,
    const u16* __restrict__ wpkM, const u16* __restrict__ wpkHM,
    float* __restrict__ out)
{
  __shared__ uint4 sm4[2048];                 // 32 KB
  char* sm = reinterpret_cast<char*>(sm4);
  int t = threadIdx.x;
  int b = blockIdx.x / 288;
  int n0 = (blockIdx.x % 288) * 32;
  // stage Hh -> c 0..255
  for (int it=0; it<4; ++it){
    int s = it*256 + t;
    int c = s >> 2, q = s & 3;
    union { u16 h[8]; uint4 u; } v;
    v.u = *reinterpret_cast<const uint4*>(Hh + ((size_t)b*CC + c)*NN + n0 + q*8);
    #pragma unroll
    for (int e=0;e<8;e++)
      *reinterpret_cast<u16*>(sm + swz(q*8+e, c)) = v.h[e];
  }
  // stage x (fp32 -> bf16) -> c 256..511
  for (int it=0; it<8; ++it){
    int s = it*256 + t;
    int c = s >> 3, q4 = s & 7;
    float4 v = *reinterpret_cast<const float4*>(x + ((size_t)b*CC + c)*NN + n0 + q4*4);
    *reinterpret_cast<u16*>(sm + swz(q4*4+0, 256+c)) = f2us(v.x);
    *reinterpret_cast<u16*>(sm + swz(q4*4+1, 256+c)) = f2us(v.y);
    *reinterpret_cast<u16*>(sm + swz(q4*4+2, 256+c)) = f2us(v.z);
    *reinterpret_cast<u16*>(sm + swz(q4*4+3, 256+c)) = f2us(v.w);
  }
  __syncthreads();
  int w = t >> 6, l = t & 63, ln = l & 15, lk = l >> 4;
  f32x4 acc[4][2];
  // ---- phase A: M = sigmoid(w_m . [Hh; x]) ----
  #pragma unroll
  for (int i=0;i<4;i++){ acc[i][0] = 0.f; acc[i][1] = 0.f; }
  for (int ks=0; ks<16; ++ks){
    bf16x8 bfr0 = *reinterpret_cast<const bf16x8*>(sm + swz(ln,    ks*32 + lk*8));
    bf16x8 bfr1 = *reinterpret_cast<const bf16x8*>(sm + swz(16+ln, ks*32 + lk*8));
    #pragma unroll
    for (int mf=0; mf<4; mf++){
      int ot = w*4 + mf;
      bf16x8 afr = *reinterpret_cast<const bf16x8*>(wpkM + ((size_t)(ot*16 + ks)*64 + l)*8);
      acc[mf][0] = __builtin_amdgcn_mfma_f32_16x16x32_bf16(afr, bfr0, acc[mf][0], 0,0,0);
      acc[mf][1] = __builtin_amdgcn_mfma_f32_16x16x32_bf16(afr, bfr1, acc[mf][1], 0,0,0);
    }
  }
  __syncthreads();   // all x-region reads done
  // M (sigmoid, bf16) overwrites x region: c 256..511
  #pragma unroll
  for (int mf=0; mf<4; mf++){
    #pragma unroll
    for (int nf=0; nf<2; nf++){
      #pragma unroll
      for (int r=0;r<4;r++){
        int o = w*64 + mf*16 + lk*4 + r;
        int n = nf*16 + ln;
        float mval = 1.f/(1.f + __expf(-acc[mf][nf][r]));
        *reinterpret_cast<u16*>(sm + swz(n, 256+o)) = f2us(mval);
      }
    }
  }
  __syncthreads();
  // ---- phase B: out = lrelu(w_hm . [Hh; M]) ----
  #pragma unroll
  for (int i=0;i<4;i++){ acc[i][0] = 0.f; acc[i][1] = 0.f; }
  for (int ks=0; ks<16; ++ks){
    bf16x8 bfr0 = *reinterpret_cast<const bf16x8*>(sm + swz(ln,    ks*32 + lk*8));
    bf16x8 bfr1 = *reinterpret_cast<const bf16x8*>(sm + swz(16+ln, ks*32 + lk*8));
    #pragma unroll
    for (int mf=0; mf<4; mf++){
      int ot = w*4 + mf;
      bf16x8 afr = *reinterpret_cast<const bf16x8*>(wpkHM + ((size_t)(ot*16 + ks)*64 + l)*8);
      acc[mf][0] = __builtin_amdgcn_mfma_f32_16x16x32_bf16(afr, bfr0, acc[mf][0], 0,0,0);
      acc[mf][1] = __builtin_amdgcn_mfma_f32_16x16x32_bf16(afr, bfr1, acc[mf][1], 0,0,0);
    }
  }
  #pragma unroll
  for (int mf=0; mf<4; mf++){
    #pragma unroll
    for (int nf=0; nf<2; nf++){
      #pragma unroll
      for (int r=0;r<4;r++){
        int o = w*64 + mf*16 + lk*4 + r;
        out[((size_t)b*CC + o)*NN + n0 + nf*16 + ln] = lrelu(acc[mf][nf][r]);
      }
    }
  }
}

extern "C" void kernel_launch(void* const* d_in, const int* in_sizes, int n_in,
                              void* d_out, int out_size, void* d_ws, size_t ws_size,
                              hipStream_t stream)
{
  const float* x     = (const float*)d_in[0];
  const float* w_f   = (const float*)d_in[1];
  const float* w_beta= (const float*)d_in[2];
  const float* w1    = (const float*)d_in[3];
  const float* w3    = (const float*)d_in[4];
  const float* w5    = (const float*)d_in[5];
  const float* w7    = (const float*)d_in[6];
  const float* w_a2b = (const float*)d_in[7];
  const float* w_f2c = (const float*)d_in[8];
  const float* w_f2d = (const float*)d_in[9];
  const float* w_e   = (const float*)d_in[10];
  const float* w_h   = (const float*)d_in[11];
  const float* w_m   = (const float*)d_in[12];
  const float* w_hm  = (const float*)d_in[13];

  char* ws = (char*)d_ws;
  size_t off = 0;
  auto alloc = [&](size_t bytes) -> void* {
    void* p = ws + off; off += (bytes + 255) & ~(size_t)255; return p;
  };
  float* F    = (float*)alloc(sizeof(float)*(size_t)BN*KK*NN);
  float* AMb  = (float*)alloc(sizeof(float)*(size_t)BN*2*NN);
  float* Bmv  = (float*)alloc(sizeof(float)*(size_t)BN*NN);
  float* Cmv  = (float*)alloc(sizeof(float)*(size_t)BN*NN);
  float* F4   = (float*)alloc(sizeof(float)*(size_t)BN*4*NN);
  float* G    = (float*)alloc(sizeof(float)*(size_t)BN*KK*CC);
  float* WSp  = (float*)alloc(sizeof(float)*(size_t)BN*CC*KK);
  float* Tsc  = (float*)alloc(sizeof(float)*(size_t)BN*NN);
  u16*   Ssp  = (u16*)alloc(sizeof(u16)*(size_t)BN*NN);
  u16*   WD   = (u16*)alloc(sizeof(u16)*(size_t)BN*CC*NN);
  u16*   o1   = (u16*)alloc(sizeof(u16)*(size_t)BN*CC*NN);
  u16*   o2   = (u16*)alloc(sizeof(u16)*(size_t)BN*CC*NN);
  u16*   Hh   = (u16*)alloc(sizeof(u16)*(size_t)BN*CC*NN);
  u16*   wpk  = (u16*)alloc(sizeof(u16)*(size_t)3*16*16*64*8);   // packed w_h/w_m/w_hm
  (void)ws_size; (void)in_sizes; (void)n_in; (void)out_size;

  u16* wpkH  = wpk;
  u16* wpkM  = wpk + (size_t)16384*8;
  u16* wpkHM = wpk + (size_t)2*16384*8;

  kw_pack <<<192, 256, 0, stream>>>(w_h, w_m, w_hm, wpk);
  k1_fx   <<<144, 256, 0, stream>>>(x, w_f, w_a2b, F, AMb, Bmv);
  k2_g    <<<512, 256, 0, stream>>>(x, F, G);
  k3_smws <<<8,   256, 0, stream>>>(G, w_beta, WSp);
  k4_out1 <<<144, 256, 0, stream>>>(F, WSp, x, o1);
  k5_conv <<<288, 256, 0, stream>>>(AMb, w1, w3, w5, w7, w_f2c, F4, Cmv);
  k6a_t   <<<8,   256, 0, stream>>>(Bmv, Cmv, Tsc);
  k6b_sm  <<<3,   256, 0, stream>>>(Tsc, Ssp);
  k7_wd   <<<1536,256, 0, stream>>>(F4, w_f2d, w_e, WD);
  k8_out2 <<<2048,256, 0, stream>>>(Ssp, WD, x, o2);
  k9m     <<<2304,256, 0, stream>>>(o1, o2, wpkH, Hh);
  k10m    <<<2304,256, 0, stream>>>(Hh, x, wpkM, wpkHM, (float*)d_out);
}

// Round 5
// 495.681 us; speedup vs baseline: 4.1789x; 1.7855x over previous
//
#include <hip/hip_runtime.h>

typedef unsigned short u16;
typedef unsigned int   u32;

#define BN 8
#define CC 256
#define HW 96
#define NN 9216   // 96*96
#define KK 16

typedef __attribute__((ext_vector_type(8))) short bf16x8;
typedef __attribute__((ext_vector_type(4))) float f32x4;

__device__ __forceinline__ float us2f(u16 u){
  union { u32 i; float f; } v; v.i = ((u32)u) << 16; return v.f;
}
__device__ __forceinline__ u16 f2us(float f){
  union { float f; u32 i; } v; v.f = f;
  u32 x = v.i;
  u32 r = (x + 0x7fffu + ((x >> 16) & 1u)) >> 16;  // RNE
  return (u16)r;
}
__device__ __forceinline__ float lrelu(float v){ return v >= 0.f ? v : 0.001f*v; }

// LDS swizzle for [32 n][512 c] bf16 tile (1024B rows)
__device__ __forceinline__ u32 swz(int n, int c){
  return (u32)(n*1024 + ((((c>>3) ^ (n&31)) & 63)<<4) + ((c&7)<<1));
}
// LDS swizzle for [64 n][256 c] bf16 tile (512B rows)
__device__ __forceinline__ u32 swz7(int n, int c){
  return (u32)(n*512 + ((((c>>3) ^ (n&31)) & 31)<<4) + ((c&7)<<1));
}
// LDS swizzle for [192 col][96 k] bf16 tile padded to 256B rows
__device__ __forceinline__ u32 swz8(int col, int k){
  return (u32)(col*256 + ((((k>>3) ^ (col&15)) & 15)<<4) + ((k&7)<<1));
}

// ---------------- K1: F = w_f.x ; Bm = lrelu(w_a2b.x) ; AM = [mean_c, max_c] ----------------
__global__ __launch_bounds__(256) void k1_fx(
    const float* __restrict__ x, const float* __restrict__ w_f, const float* __restrict__ w_a2b,
    float* __restrict__ F, float* __restrict__ AM, float* __restrict__ Bm)
{
  __shared__ float wf[CC][KK];   // [c][k]
  __shared__ float wa[CC];
  int t = threadIdx.x;
  for (int i = t; i < KK*CC; i += 256) wf[i & 255][i >> 8] = w_f[i];
  wa[t] = w_a2b[t];
  __syncthreads();
  int pid = blockIdx.x*256 + t;             // 2 pixels per thread
  int b = pid / (NN/2);
  int n = (pid % (NN/2)) * 2;
  const float* xp = x + (size_t)b*CC*NN + n;
  float a0[KK], a1[KK];
  #pragma unroll
  for (int k=0;k<KK;k++){ a0[k]=0.f; a1[k]=0.f; }
  float s0=0.f,s1=0.f,m0=-3e38f,m1=-3e38f,b0=0.f,b1=0.f;
  for (int c=0;c<CC;c++){
    float2 xv = *reinterpret_cast<const float2*>(xp + (size_t)c*NN);
    float v0 = xv.x, v1 = xv.y;
    s0 += v0; s1 += v1;
    m0 = fmaxf(m0, v0); m1 = fmaxf(m1, v1);
    b0 = fmaf(wa[c], v0, b0); b1 = fmaf(wa[c], v1, b1);
    const float* wr = wf[c];
    #pragma unroll
    for (int k=0;k<KK;k++){ a0[k] = fmaf(wr[k], v0, a0[k]); a1[k] = fmaf(wr[k], v1, a1[k]); }
  }
  float* Fp = F + (size_t)b*KK*NN + n;
  #pragma unroll
  for (int k=0;k<KK;k++){ float2 f2; f2.x=a0[k]; f2.y=a1[k];
    *reinterpret_cast<float2*>(Fp + (size_t)k*NN) = f2; }
  float2 av; av.x = s0*(1.f/256.f); av.y = s1*(1.f/256.f);
  float2 mx; mx.x = m0; mx.y = m1;
  *reinterpret_cast<float2*>(AM + (size_t)b*2*NN + n) = av;
  *reinterpret_cast<float2*>(AM + (size_t)b*2*NN + NN + n) = mx;
  float2 bm; bm.x = lrelu(b0); bm.y = lrelu(b1);
  *reinterpret_cast<float2*>(Bm + (size_t)b*NN + n) = bm;
}

// ---------------- K2: G[b,k,c] = sum_n F[b,k,n]*x[b,c,n]  (4 c per block) ----------------
__global__ __launch_bounds__(256) void k2_g(
    const float* __restrict__ x, const float* __restrict__ F, float* __restrict__ G)
{
  int b = blockIdx.x >> 6;
  int c0 = (blockIdx.x & 63) * 4;
  int t = threadIdx.x;
  const float* Fp = F + (size_t)b*KK*NN;
  const float* xp = x + ((size_t)b*CC + c0)*NN;
  float acc[KK][4];
  #pragma unroll
  for (int k=0;k<KK;k++){ acc[k][0]=acc[k][1]=acc[k][2]=acc[k][3]=0.f; }
  for (int n = t; n < NN; n += 256){
    float xv0 = xp[n];
    float xv1 = xp[(size_t)NN + n];
    float xv2 = xp[(size_t)2*NN + n];
    float xv3 = xp[(size_t)3*NN + n];
    #pragma unroll
    for (int k=0;k<KK;k++){
      float fv = Fp[(size_t)k*NN + n];
      acc[k][0] = fmaf(fv, xv0, acc[k][0]);
      acc[k][1] = fmaf(fv, xv1, acc[k][1]);
      acc[k][2] = fmaf(fv, xv2, acc[k][2]);
      acc[k][3] = fmaf(fv, xv3, acc[k][3]);
    }
  }
  #pragma unroll
  for (int k=0;k<KK;k++){
    #pragma unroll
    for (int i=0;i<4;i++){
      float v = acc[k][i];
      for (int off=32; off>0; off>>=1) v += __shfl_down(v, off);
      acc[k][i] = v;
    }
  }
  __shared__ float part[4][KK][4];
  int lane = t & 63, wv = t >> 6;
  if (lane == 0){
    #pragma unroll
    for (int k=0;k<KK;k++){ part[wv][k][0]=acc[k][0]; part[wv][k][1]=acc[k][1];
                            part[wv][k][2]=acc[k][2]; part[wv][k][3]=acc[k][3]; }
  }
  __syncthreads();
  if (t < 64){
    int k = t >> 2, i = t & 3;
    float s = part[0][k][i] + part[1][k][i] + part[2][k][i] + part[3][k][i];
    G[((size_t)b*KK + k)*CC + c0 + i] = s;
  }
}

// ---------------- K3: S = softmax_c(G) ; WS[b,o,k] = sum_c w_beta[o,c]*S[b,k,c] ----------------
__global__ __launch_bounds__(256) void k3_smws(
    const float* __restrict__ G, const float* __restrict__ w_beta, float* __restrict__ WSp)
{
  int b = blockIdx.x, t = threadIdx.x;
  __shared__ float sl[KK][CC];
  for (int k=0;k<KK;k++) sl[k][t] = G[((size_t)b*KK + k)*CC + t];
  __syncthreads();
  int lane = t & 63, wv = t >> 6;
  for (int r=0;r<4;r++){
    int k = wv*4 + r;
    float v0 = sl[k][lane], v1 = sl[k][lane+64], v2 = sl[k][lane+128], v3 = sl[k][lane+192];
    float m = fmaxf(fmaxf(v0,v1), fmaxf(v2,v3));
    for (int off=32; off>0; off>>=1) m = fmaxf(m, __shfl_xor(m, off));
    float e0=__expf(v0-m), e1=__expf(v1-m), e2=__expf(v2-m), e3=__expf(v3-m);
    float s = e0+e1+e2+e3;
    for (int off=32; off>0; off>>=1) s += __shfl_xor(s, off);
    float inv = 1.f/s;
    sl[k][lane]=e0*inv; sl[k][lane+64]=e1*inv; sl[k][lane+128]=e2*inv; sl[k][lane+192]=e3*inv;
  }
  __syncthreads();
  const float* wb = w_beta + (size_t)t*CC;
  float acc[KK];
  #pragma unroll
  for (int k=0;k<KK;k++) acc[k]=0.f;
  for (int c=0;c<CC;c++){
    float w = wb[c];
    #pragma unroll
    for (int k=0;k<KK;k++) acc[k] = fmaf(w, sl[k][c], acc[k]);
  }
  float* wsp = WSp + ((size_t)b*CC + t)*KK;
  #pragma unroll
  for (int k=0;k<KK;k++) wsp[k] = acc[k];
}

// ---------------- K4: out1[b,o,n] = sum_k WS[b,o,k]*F[b,k,n] + x[b,o,n]  -> bf16 ----------------
__global__ __launch_bounds__(256) void k4_out1(
    const float* __restrict__ F, const float* __restrict__ WSp,
    const float* __restrict__ x, u16* __restrict__ out1)
{
  __shared__ float ws[CC][KK];
  int t = threadIdx.x;
  int pid = blockIdx.x*256 + t;
  int b = pid / (NN/2);
  int n = (pid % (NN/2)) * 2;
  const float* wsg = WSp + (size_t)b*CC*KK;
  for (int i=t; i<CC*KK; i+=256) ws[i>>4][i&15] = wsg[i];
  __syncthreads();
  float f0[KK], f1[KK];
  const float* Fp = F + (size_t)b*KK*NN + n;
  #pragma unroll
  for (int k=0;k<KK;k++){
    float2 f2 = *reinterpret_cast<const float2*>(Fp + (size_t)k*NN);
    f0[k]=f2.x; f1[k]=f2.y;
  }
  const float* xp = x + (size_t)b*CC*NN + n;
  u16* op = out1 + (size_t)b*CC*NN + n;
  for (int o=0;o<CC;o++){
    float2 xv = *reinterpret_cast<const float2*>(xp + (size_t)o*NN);
    float v0 = xv.x, v1 = xv.y;
    const float* wr = ws[o];
    #pragma unroll
    for (int k=0;k<KK;k++){ v0 = fmaf(wr[k], f0[k], v0); v1 = fmaf(wr[k], f1[k], v1); }
    union { u16 h[2]; u32 u; } pk;
    pk.h[0] = f2us(v0); pk.h[1] = f2us(v1);
    *reinterpret_cast<u32*>(op + (size_t)o*NN) = pk.u;
  }
}

// ---------------- K5: spatial convs -> F4, Cm ----------------
__global__ __launch_bounds__(256) void k5_conv(
    const float* __restrict__ AM, const float* __restrict__ w1, const float* __restrict__ w3,
    const float* __restrict__ w5, const float* __restrict__ w7, const float* __restrict__ wf2c,
    float* __restrict__ F4, float* __restrict__ Cm)
{
  __shared__ float w3l[18], w5l[50], w7l[98], w1l[2], wcl[4];
  int t = threadIdx.x;
  if (t < 2)  w1l[t] = w1[t];
  if (t < 18) w3l[t] = w3[t];
  if (t < 50) w5l[t] = w5[t];
  if (t < 98) w7l[t] = w7[t];
  if (t < 4)  wcl[t] = wf2c[t];
  __syncthreads();
  int gid = blockIdx.x*256 + t;
  int b = gid / NN, n = gid % NN;
  int h = n / HW, w = n % HW;
  const float* am = AM + (size_t)b*2*NN;
  float a0 = am[n], a1 = am[NN + n];
  float s1v = lrelu(a0*w1l[0] + a1*w1l[1]);
  float s3v=0.f, s5v=0.f, s7v=0.f;
  for (int p=-3;p<=3;p++){
    int hh = h + p;
    if (hh < 0 || hh >= HW) continue;
    for (int q=-3;q<=3;q++){
      int ww = w + q;
      if (ww < 0 || ww >= HW) continue;
      float v0 = am[hh*HW+ww], v1 = am[NN + hh*HW + ww];
      s7v += v0*w7l[(p+3)*7 + (q+3)] + v1*w7l[49 + (p+3)*7 + (q+3)];
      if (p>=-2 && p<=2 && q>=-2 && q<=2)
        s5v += v0*w5l[(p+2)*5 + (q+2)] + v1*w5l[25 + (p+2)*5 + (q+2)];
      if (p>=-1 && p<=1 && q>=-1 && q<=1)
        s3v += v0*w3l[(p+1)*3 + (q+1)] + v1*w3l[9 + (p+1)*3 + (q+1)];
    }
  }
  s3v = lrelu(s3v); s5v = lrelu(s5v); s7v = lrelu(s7v);
  float* f4p = F4 + (size_t)b*4*NN + n;
  f4p[0] = s1v; f4p[NN] = s3v; f4p[2*(size_t)NN] = s5v; f4p[3*(size_t)NN] = s7v;
  Cm[(size_t)b*NN + n] = lrelu(s1v*wcl[0] + s3v*wcl[1] + s5v*wcl[2] + s7v*wcl[3]);
}

// ---------------- K6a: T[b,h,k] = sum_w Bm[b,h*96+w]*Cm[b,w*96+k] ----------------
__global__ __launch_bounds__(256) void k6a_t(
    const float* __restrict__ Bm, const float* __restrict__ Cm, float* __restrict__ Tsc)
{
  __shared__ float Cl[NN];
  int b = blockIdx.x, t = threadIdx.x;
  for (int i=t;i<NN;i+=256) Cl[i] = Cm[(size_t)b*NN + i];
  __syncthreads();
  const float* bp = Bm + (size_t)b*NN;
  for (int g=0; g<9; g++){
    int idx4 = (t + 256*g)*4;
    int h = idx4/96, k0 = idx4%96;
    float a0=0.f,a1=0.f,a2=0.f,a3=0.f;
    const float* brow = bp + h*96;
    for (int w2=0;w2<96;w2++){
      float bv = brow[w2];
      float4 cv = *reinterpret_cast<const float4*>(&Cl[w2*96 + k0]);
      a0=fmaf(bv,cv.x,a0); a1=fmaf(bv,cv.y,a1); a2=fmaf(bv,cv.z,a2); a3=fmaf(bv,cv.w,a3);
    }
    float4 o4; o4.x=a0; o4.y=a1; o4.z=a2; o4.w=a3;
    *reinterpret_cast<float4*>(Tsc + (size_t)b*NN + idx4) = o4;
  }
}

// ---------------- K6b: Ssp = softmax_k(T), packed directly into MFMA A-frag layout ----------------
// spk[b][mf][ks][lane][e] = S[b][mf*16 + (lane&15)][ks*32 + (lane>>4)*8 + e]
__global__ __launch_bounds__(256) void k6b_sm(
    const float* __restrict__ Tsc, u16* __restrict__ spk)
{
  int gid = blockIdx.x*256 + threadIdx.x;
  if (gid >= BN*96) return;
  int b = gid/96, h = gid%96;
  const float* row = Tsc + (size_t)b*NN + h*96;
  float m = -3e38f;
  for (int k=0;k<96;k++) m = fmaxf(m, row[k]);
  float s = 0.f;
  for (int k=0;k<96;k++) s += __expf(row[k]-m);
  float inv = 1.f/s;
  int mf = h >> 4;
  for (int g=0; g<12; g++){
    int ks = g >> 2, lk = g & 3;
    union { u16 hh[8]; uint4 u; } pk;
    #pragma unroll
    for (int e=0;e<8;e++) pk.hh[e] = f2us(__expf(row[g*8+e]-m)*inv);
    *reinterpret_cast<uint4*>(spk + ((size_t)(((b*6 + mf)*3 + ks)*64) + lk*16 + (h&15))*8) = pk.u;
  }
}

// ---------------- KW: pack w_h / w_m / w_hm (256x512) and w_e (256x256) into bf16 A-frag order ----------------
__global__ __launch_bounds__(256) void kw_pack(
    const float* __restrict__ w_h, const float* __restrict__ w_m,
    const float* __restrict__ w_hm, const float* __restrict__ w_e,
    u16* __restrict__ wpk, u16* __restrict__ wpkE)
{
  int gid = blockIdx.x*256 + threadIdx.x;   // 57344
  if (gid < 49152){
    int mat = gid >> 14;
    int r = gid & 16383;
    int ot = r >> 10;
    int ks = (r >> 6) & 15;
    int l  = r & 63;
    const float* W = (mat==0) ? w_h : ((mat==1) ? w_m : w_hm);
    int o = ot*16 + (l & 15);
    int c = ks*32 + (l >> 4)*8;
    const float* src = W + (size_t)o*512 + c;
    union { u16 h[8]; uint4 u; } pk;
    #pragma unroll
    for (int e=0;e<8;e++) pk.h[e] = f2us(src[e]);
    *reinterpret_cast<uint4*>(wpk + (size_t)gid*8) = pk.u;
  } else {
    int r = gid - 49152;                    // 8192 frags for w_e (K=256)
    int ot = r >> 9;
    int ks = (r >> 6) & 7;
    int l  = r & 63;
    int o = ot*16 + (l & 15);
    int c = ks*32 + (l >> 4)*8;
    const float* src = w_e + (size_t)o*256 + c;
    union { u16 h[8]; uint4 u; } pk;
    #pragma unroll
    for (int e=0;e<8;e++) pk.h[e] = f2us(src[e]);
    *reinterpret_cast<uint4*>(wpkE + (size_t)r*8) = pk.u;
  }
}

// ---------------- K7M: WD = w_e . lrelu(w_f2d . F4) — MFMA, M=256 N=64 K=256 per block ----------------
__global__ __launch_bounds__(256) void k7m(
    const float* __restrict__ F4, const float* __restrict__ w_f2d,
    const u16* __restrict__ wpkE, u16* __restrict__ WD)
{
  __shared__ uint4 sm4[2048];               // 32 KB: [64 n][256 c] bf16 swizzled
  char* sm = reinterpret_cast<char*>(sm4);
  int t = threadIdx.x;
  int b = blockIdx.x / 144;
  int n0 = (blockIdx.x % 144) * 64;
  int n = t & 63, cg = t >> 6;              // this thread: pixel n, c-range cg*64..+64
  float f0 = F4[((size_t)b*4+0)*NN + n0 + n];
  float f1 = F4[((size_t)b*4+1)*NN + n0 + n];
  float f2 = F4[((size_t)b*4+2)*NN + n0 + n];
  float f3 = F4[((size_t)b*4+3)*NN + n0 + n];
  for (int c8 = 0; c8 < 8; ++c8){
    int c = cg*64 + c8*8;
    union { u16 h[8]; uint4 u; } pk;
    #pragma unroll
    for (int e=0;e<8;e++){
      const float* wfp = w_f2d + (size_t)(c+e)*4;
      pk.h[e] = f2us(lrelu(fmaf(wfp[0],f0, fmaf(wfp[1],f1, fmaf(wfp[2],f2, wfp[3]*f3)))));
    }
    *reinterpret_cast<uint4*>(sm + swz7(n, c)) = pk.u;
  }
  __syncthreads();
  int w = t >> 6, l = t & 63, ln = l & 15, lk = l >> 4;
  f32x4 acc[4][4];
  #pragma unroll
  for (int i=0;i<4;i++){ acc[i][0]=0.f; acc[i][1]=0.f; acc[i][2]=0.f; acc[i][3]=0.f; }
  for (int ks=0; ks<8; ++ks){
    bf16x8 bfr[4];
    #pragma unroll
    for (int nf=0; nf<4; nf++)
      bfr[nf] = *reinterpret_cast<const bf16x8*>(sm + swz7(nf*16 + ln, ks*32 + lk*8));
    #pragma unroll
    for (int mf=0; mf<4; mf++){
      bf16x8 afr = *reinterpret_cast<const bf16x8*>(wpkE + ((size_t)((w*4+mf)*8 + ks)*64 + l)*8);
      #pragma unroll
      for (int nf=0; nf<4; nf++)
        acc[mf][nf] = __builtin_amdgcn_mfma_f32_16x16x32_bf16(afr, bfr[nf], acc[mf][nf], 0,0,0);
    }
  }
  #pragma unroll
  for (int mf=0; mf<4; mf++){
    #pragma unroll
    for (int nf=0; nf<4; nf++){
      #pragma unroll
      for (int r=0;r<4;r++){
        int o = (w*4+mf)*16 + lk*4 + r;
        WD[((size_t)b*CC + o)*NN + n0 + nf*16 + ln] = f2us(acc[mf][nf][r]);
      }
    }
  }
}

// ---------------- K8M: out2 = Ssp x WD + x — MFMA, M=96(h) N=192(2o x 96w) K=96 per block ----------------
__global__ __launch_bounds__(256) void k8m(
    const u16* __restrict__ WD, const u16* __restrict__ spk,
    const float* __restrict__ x, u16* __restrict__ out2)
{
  __shared__ uint4 sm4[3072];               // 48 KB: [192 col][128 k-pad] bf16 swizzled
  char* sm = reinterpret_cast<char*>(sm4);
  int t = threadIdx.x;
  int b = blockIdx.x >> 7;
  int o0 = (blockIdx.x & 127) * 2;
  // stage WD 2 channels, transposed to [col][k]
  for (int it=0; it<9; ++it){
    int s = it*256 + t;                     // 0..2303
    int w16 = s % 12;
    int k   = (s / 12) % 96;
    int oi  = s / 1152;
    union { u16 h[8]; uint4 u; } v;
    v.u = *reinterpret_cast<const uint4*>(WD + ((size_t)b*CC + o0+oi)*NN + k*96 + w16*8);
    #pragma unroll
    for (int e=0;e<8;e++){
      int col = oi*96 + w16*8 + e;
      *reinterpret_cast<u16*>(sm + swz8(col, k)) = v.h[e];
    }
  }
  __syncthreads();
  int w = t >> 6, l = t & 63, ln = l & 15, lk = l >> 4;
  f32x4 acc[6][3];
  #pragma unroll
  for (int i=0;i<6;i++){ acc[i][0]=0.f; acc[i][1]=0.f; acc[i][2]=0.f; }
  for (int ks=0; ks<3; ++ks){
    bf16x8 bfr[3];
    #pragma unroll
    for (int j=0;j<3;j++){
      int col = (w*3 + j)*16 + ln;
      bfr[j] = *reinterpret_cast<const bf16x8*>(sm + swz8(col, ks*32 + lk*8));
    }
    #pragma unroll
    for (int mf=0; mf<6; mf++){
      bf16x8 afr = *reinterpret_cast<const bf16x8*>(spk + ((size_t)(((b*6 + mf)*3 + ks)*64) + l)*8);
      #pragma unroll
      for (int j=0;j<3;j++)
        acc[mf][j] = __builtin_amdgcn_mfma_f32_16x16x32_bf16(afr, bfr[j], acc[mf][j], 0,0,0);
    }
  }
  #pragma unroll
  for (int j=0;j<3;j++){
    int col = (w*3 + j)*16 + ln;
    int oi = (col >= 96) ? 1 : 0;
    int ww = col - 96*oi;
    const float* xp = x + ((size_t)b*CC + o0+oi)*NN + ww;
    u16* op = out2 + ((size_t)b*CC + o0+oi)*NN + ww;
    #pragma unroll
    for (int mf=0; mf<6; mf++){
      #pragma unroll
      for (int r=0;r<4;r++){
        int h = mf*16 + lk*4 + r;
        op[(size_t)h*96] = f2us(acc[mf][j][r] + xp[(size_t)h*96]);
      }
    }
  }
}

// ---------------- K9M: Hh = lrelu(w_h.[out1,out2])  — MFMA ----------------
__global__ __launch_bounds__(256) void k9m(
    const u16* __restrict__ o1, const u16* __restrict__ o2,
    const u16* __restrict__ wpk, u16* __restrict__ Hh)
{
  __shared__ uint4 sm4[2048];                 // 32 KB: [32 n][512 c] bf16, swizzled
  char* sm = reinterpret_cast<char*>(sm4);
  int t = threadIdx.x;
  int b = blockIdx.x / 288;
  int n0 = (blockIdx.x % 288) * 32;
  for (int it=0; it<8; ++it){
    int s = it*256 + t;
    int c = s >> 2, q = s & 3;
    const u16* src = (c < 256) ? (o1 + ((size_t)b*CC + c)*NN)
                               : (o2 + ((size_t)b*CC + (c-256))*NN);
    union { u16 h[8]; uint4 u; } v;
    v.u = *reinterpret_cast<const uint4*>(src + n0 + q*8);
    #pragma unroll
    for (int e=0;e<8;e++)
      *reinterpret_cast<u16*>(sm + swz(q*8+e, c)) = v.h[e];
  }
  __syncthreads();
  int w = t >> 6, l = t & 63, ln = l & 15, lk = l >> 4;
  f32x4 acc[4][2];
  #pragma unroll
  for (int i=0;i<4;i++){ acc[i][0] = 0.f; acc[i][1] = 0.f; }
  for (int ks=0; ks<16; ++ks){
    bf16x8 bfr0 = *reinterpret_cast<const bf16x8*>(sm + swz(ln,    ks*32 + lk*8));
    bf16x8 bfr1 = *reinterpret_cast<const bf16x8*>(sm + swz(16+ln, ks*32 + lk*8));
    #pragma unroll
    for (int mf=0; mf<4; mf++){
      int ot = w*4 + mf;
      bf16x8 afr = *reinterpret_cast<const bf16x8*>(wpk + ((size_t)(ot*16 + ks)*64 + l)*8);
      acc[mf][0] = __builtin_amdgcn_mfma_f32_16x16x32_bf16(afr, bfr0, acc[mf][0], 0,0,0);
      acc[mf][1] = __builtin_amdgcn_mfma_f32_16x16x32_bf16(afr, bfr1, acc[mf][1], 0,0,0);
    }
  }
  #pragma unroll
  for (int mf=0; mf<4; mf++){
    #pragma unroll
    for (int nf=0; nf<2; nf++){
      #pragma unroll
      for (int r=0;r<4;r++){
        int o = w*64 + mf*16 + lk*4 + r;
        Hh[((size_t)b*CC + o)*NN + n0 + nf*16 + ln] = f2us(lrelu(acc[mf][nf][r]));
      }
    }
  }
}

// ---------------- K10M: M = sigmoid(w_m.[Hh,x]); out = lrelu(w_hm.[Hh,M]) — MFMA, fp32 out ----------------
__global__ __launch_bounds__(256) void k10m(
    const u16* __restrict__ Hh, const float* __restrict__ x,
    const u16* __restrict__ wpkM, const u16* __restrict__ wpkHM,
    float* __restrict__ out)
{
  __shared__ uint4 sm4[2048];                 // 32 KB
  char* sm = reinterpret_cast<char*>(sm4);
  int t = threadIdx.x;
  int b = blockIdx.x / 288;
  int n0 = (blockIdx.x % 288) * 32;
  for (int it=0; it<4; ++it){
    int s = it*256 + t;
    int c = s >> 2, q = s & 3;
    union { u16 h[8]; uint4 u; } v;
    v.u = *reinterpret_cast<const uint4*>(Hh + ((size_t)b*CC + c)*NN + n0 + q*8);
    #pragma unroll
    for (int e=0;e<8;e++)
      *reinterpret_cast<u16*>(sm + swz(q*8+e, c)) = v.h[e];
  }
  for (int it=0; it<8; ++it){
    int s = it*256 + t;
    int c = s >> 3, q4 = s & 7;
    float4 v = *reinterpret_cast<const float4*>(x + ((size_t)b*CC + c)*NN + n0 + q4*4);
    *reinterpret_cast<u16*>(sm + swz(q4*4+0, 256+c)) = f2us(v.x);
    *reinterpret_cast<u16*>(sm + swz(q4*4+1, 256+c)) = f2us(v.y);
    *reinterpret_cast<u16*>(sm + swz(q4*4+2, 256+c)) = f2us(v.z);
    *reinterpret_cast<u16*>(sm + swz(q4*4+3, 256+c)) = f2us(v.w);
  }
  __syncthreads();
  int w = t >> 6, l = t & 63, ln = l & 15, lk = l >> 4;
  f32x4 acc[4][2];
  #pragma unroll
  for (int i=0;i<4;i++){ acc[i][0] = 0.f; acc[i][1] = 0.f; }
  for (int ks=0; ks<16; ++ks){
    bf16x8 bfr0 = *reinterpret_cast<const bf16x8*>(sm + swz(ln,    ks*32 + lk*8));
    bf16x8 bfr1 = *reinterpret_cast<const bf16x8*>(sm + swz(16+ln, ks*32 + lk*8));
    #pragma unroll
    for (int mf=0; mf<4; mf++){
      int ot = w*4 + mf;
      bf16x8 afr = *reinterpret_cast<const bf16x8*>(wpkM + ((size_t)(ot*16 + ks)*64 + l)*8);
      acc[mf][0] = __builtin_amdgcn_mfma_f32_16x16x32_bf16(afr, bfr0, acc[mf][0], 0,0,0);
      acc[mf][1] = __builtin_amdgcn_mfma_f32_16x16x32_bf16(afr, bfr1, acc[mf][1], 0,0,0);
    }
  }
  __syncthreads();
  #pragma unroll
  for (int mf=0; mf<4; mf++){
    #pragma unroll
    for (int nf=0; nf<2; nf++){
      #pragma unroll
      for (int r=0;r<4;r++){
        int o = w*64 + mf*16 + lk*4 + r;
        int n = nf*16 + ln;
        float mval = 1.f/(1.f + __expf(-acc[mf][nf][r]));
        *reinterpret_cast<u16*>(sm + swz(n, 256+o)) = f2us(mval);
      }
    }
  }
  __syncthreads();
  #pragma unroll
  for (int i=0;i<4;i++){ acc[i][0] = 0.f; acc[i][1] = 0.f; }
  for (int ks=0; ks<16; ++ks){
    bf16x8 bfr0 = *reinterpret_cast<const bf16x8*>(sm + swz(ln,    ks*32 + lk*8));
    bf16x8 bfr1 = *reinterpret_cast<const bf16x8*>(sm + swz(16+ln, ks*32 + lk*8));
    #pragma unroll
    for (int mf=0; mf<4; mf++){
      int ot = w*4 + mf;
      bf16x8 afr = *reinterpret_cast<const bf16x8*>(wpkHM + ((size_t)(ot*16 + ks)*64 + l)*8);
      acc[mf][0] = __builtin_amdgcn_mfma_f32_16x16x32_bf16(afr, bfr0, acc[mf][0], 0,0,0);
      acc[mf][1] = __builtin_amdgcn_mfma_f32_16x16x32_bf16(afr, bfr1, acc[mf][1], 0,0,0);
    }
  }
  #pragma unroll
  for (int mf=0; mf<4; mf++){
    #pragma unroll
    for (int nf=0; nf<2; nf++){
      #pragma unroll
      for (int r=0;r<4;r++){
        int o = w*64 + mf*16 + lk*4 + r;
        out[((size_t)b*CC + o)*NN + n0 + nf*16 + ln] = lrelu(acc[mf][nf][r]);
      }
    }
  }
}

extern "C" void kernel_launch(void* const* d_in, const int* in_sizes, int n_in,
                              void* d_out, int out_size, void* d_ws, size_t ws_size,
                              hipStream_t stream)
{
  const float* x     = (const float*)d_in[0];
  const float* w_f   = (const float*)d_in[1];
  const float* w_beta= (const float*)d_in[2];
  const float* w1    = (const float*)d_in[3];
  const float* w3    = (const float*)d_in[4];
  const float* w5    = (const float*)d_in[5];
  const float* w7    = (const float*)d_in[6];
  const float* w_a2b = (const float*)d_in[7];
  const float* w_f2c = (const float*)d_in[8];
  const float* w_f2d = (const float*)d_in[9];
  const float* w_e   = (const float*)d_in[10];
  const float* w_h   = (const float*)d_in[11];
  const float* w_m   = (const float*)d_in[12];
  const float* w_hm  = (const float*)d_in[13];

  char* ws = (char*)d_ws;
  size_t off = 0;
  auto alloc = [&](size_t bytes) -> void* {
    void* p = ws + off; off += (bytes + 255) & ~(size_t)255; return p;
  };
  float* F    = (float*)alloc(sizeof(float)*(size_t)BN*KK*NN);
  float* AMb  = (float*)alloc(sizeof(float)*(size_t)BN*2*NN);
  float* Bmv  = (float*)alloc(sizeof(float)*(size_t)BN*NN);
  float* Cmv  = (float*)alloc(sizeof(float)*(size_t)BN*NN);
  float* F4   = (float*)alloc(sizeof(float)*(size_t)BN*4*NN);
  float* G    = (float*)alloc(sizeof(float)*(size_t)BN*KK*CC);
  float* WSp  = (float*)alloc(sizeof(float)*(size_t)BN*CC*KK);
  float* Tsc  = (float*)alloc(sizeof(float)*(size_t)BN*NN);
  u16*   spk  = (u16*)alloc(sizeof(u16)*(size_t)BN*NN);           // packed softmax S
  u16*   WD   = (u16*)alloc(sizeof(u16)*(size_t)BN*CC*NN);
  u16*   o1   = (u16*)alloc(sizeof(u16)*(size_t)BN*CC*NN);
  u16*   o2   = (u16*)alloc(sizeof(u16)*(size_t)BN*CC*NN);
  u16*   Hh   = (u16*)alloc(sizeof(u16)*(size_t)BN*CC*NN);
  u16*   wpk  = (u16*)alloc(sizeof(u16)*(size_t)3*16384*8);       // packed w_h/w_m/w_hm
  u16*   wpkE = (u16*)alloc(sizeof(u16)*(size_t)8192*8);          // packed w_e
  (void)ws_size; (void)in_sizes; (void)n_in; (void)out_size;

  u16* wpkH  = wpk;
  u16* wpkM  = wpk + (size_t)16384*8;
  u16* wpkHM = wpk + (size_t)2*16384*8;

  kw_pack <<<224, 256, 0, stream>>>(w_h, w_m, w_hm, w_e, wpk, wpkE);
  k1_fx   <<<144, 256, 0, stream>>>(x, w_f, w_a2b, F, AMb, Bmv);
  k2_g    <<<512, 256, 0, stream>>>(x, F, G);
  k3_smws <<<8,   256, 0, stream>>>(G, w_beta, WSp);
  k4_out1 <<<144, 256, 0, stream>>>(F, WSp, x, o1);
  k5_conv <<<288, 256, 0, stream>>>(AMb, w1, w3, w5, w7, w_f2c, F4, Cmv);
  k6a_t   <<<8,   256, 0, stream>>>(Bmv, Cmv, Tsc);
  k6b_sm  <<<3,   256, 0, stream>>>(Tsc, spk);
  k7m     <<<1152,256, 0, stream>>>(F4, w_f2d, wpkE, WD);
  k8m     <<<1024,256, 0, stream>>>(WD, spk, x, o2);
  k9m     <<<2304,256, 0, stream>>>(o1, o2, wpkH, Hh);
  k10m    <<<2304,256, 0, stream>>>(Hh, x, wpkM, wpkHM, (float*)d_out);
}

// Round 6
// 435.402 us; speedup vs baseline: 4.7574x; 1.1384x over previous
//
#include <hip/hip_runtime.h>

typedef unsigned short u16;
typedef unsigned int   u32;
typedef unsigned long long u64;

#define BN 8
#define CC 256
#define HW 96
#define NN 9216   // 96*96
#define KK 16

typedef __attribute__((ext_vector_type(8))) short bf16x8;
typedef __attribute__((ext_vector_type(4))) float f32x4;

__device__ __forceinline__ float us2f(u16 u){
  union { u32 i; float f; } v; v.i = ((u32)u) << 16; return v.f;
}
__device__ __forceinline__ u16 f2us(float f){
  union { float f; u32 i; } v; v.f = f;
  u32 x = v.i;
  u32 r = (x + 0x7fffu + ((x >> 16) & 1u)) >> 16;  // RNE
  return (u16)r;
}
__device__ __forceinline__ float lrelu(float v){ return v >= 0.f ? v : 0.001f*v; }

// LDS swizzle for [32 n][256 c] bf16 tile (512B rows), 16B granules
__device__ __forceinline__ u32 swz2(int n, int c){
  return (u32)(n*512 + ((((c>>3) ^ (n&31)) & 31)<<4) + ((c&7)<<1));
}
// LDS swizzle for [64 n][256 c] bf16 tile (512B rows)
__device__ __forceinline__ u32 swz7(int n, int c){
  return (u32)(n*512 + ((((c>>3) ^ (n&31)) & 31)<<4) + ((c&7)<<1));
}
// LDS swizzle for [192 col][96 k] bf16 tile padded to 256B rows
__device__ __forceinline__ u32 swz8(int col, int k){
  return (u32)(col*256 + ((((k>>3) ^ (col&15)) & 15)<<4) + ((k&7)<<1));
}

// ---------------- K1: F = w_f.x ; Bm = lrelu(w_a2b.x) ; AM = [mean,max] ; xf = x bf16 B-frags ----------------
__global__ __launch_bounds__(256) void k1_fx(
    const float* __restrict__ x, const float* __restrict__ w_f, const float* __restrict__ w_a2b,
    float* __restrict__ F, float* __restrict__ AM, float* __restrict__ Bm, u16* __restrict__ xf)
{
  __shared__ float wf[CC][KK];   // [c][k]
  __shared__ float wa[CC];
  int t = threadIdx.x;
  for (int i = t; i < KK*CC; i += 256) wf[i & 255][i >> 8] = w_f[i];
  wa[t] = w_a2b[t];
  __syncthreads();
  int pid = blockIdx.x*256 + t;             // 1 pixel per thread, 288 blocks
  int b = pid / NN;
  int n = pid % NN;
  const float* xp = x + (size_t)b*CC*NN + n;
  float a0[KK];
  #pragma unroll
  for (int k=0;k<KK;k++) a0[k]=0.f;
  float s0=0.f, m0=-3e38f, b0=0.f;
  int nt = n >> 4, lnn = n & 15;
  u16* xfb = xf + ((size_t)(b*576 + nt)*8)*512;   // ks*512 + lane*8 + e  (u16 units)
  union { u16 h[8]; uint4 u; } pk;
  for (int c=0;c<CC;c++){
    float v = xp[(size_t)c*NN];
    s0 += v;
    m0 = fmaxf(m0, v);
    b0 = fmaf(wa[c], v, b0);
    const float* wr = wf[c];
    #pragma unroll
    for (int k=0;k<KK;k++) a0[k] = fmaf(wr[k], v, a0[k]);
    pk.h[c & 7] = f2us(v);
    if ((c & 7) == 7){
      int ks = c >> 5, lkq = (c >> 3) & 3;
      *reinterpret_cast<uint4*>(xfb + ((size_t)ks*64 + lkq*16 + lnn)*8) = pk.u;
    }
  }
  float* Fp = F + (size_t)b*KK*NN + n;
  #pragma unroll
  for (int k=0;k<KK;k++) Fp[(size_t)k*NN] = a0[k];
  AM[(size_t)b*2*NN + n] = s0*(1.f/256.f);
  AM[(size_t)b*2*NN + NN + n] = m0;
  Bm[(size_t)b*NN + n] = lrelu(b0);
}

// ---------------- K2: G[b,k,c] = sum_n F[b,k,n]*x[b,c,n]  (4 c per block) ----------------
__global__ __launch_bounds__(256) void k2_g(
    const float* __restrict__ x, const float* __restrict__ F, float* __restrict__ G)
{
  int b = blockIdx.x >> 6;
  int c0 = (blockIdx.x & 63) * 4;
  int t = threadIdx.x;
  const float* Fp = F + (size_t)b*KK*NN;
  const float* xp = x + ((size_t)b*CC + c0)*NN;
  float acc[KK][4];
  #pragma unroll
  for (int k=0;k<KK;k++){ acc[k][0]=acc[k][1]=acc[k][2]=acc[k][3]=0.f; }
  for (int n = t; n < NN; n += 256){
    float xv0 = xp[n];
    float xv1 = xp[(size_t)NN + n];
    float xv2 = xp[(size_t)2*NN + n];
    float xv3 = xp[(size_t)3*NN + n];
    #pragma unroll
    for (int k=0;k<KK;k++){
      float fv = Fp[(size_t)k*NN + n];
      acc[k][0] = fmaf(fv, xv0, acc[k][0]);
      acc[k][1] = fmaf(fv, xv1, acc[k][1]);
      acc[k][2] = fmaf(fv, xv2, acc[k][2]);
      acc[k][3] = fmaf(fv, xv3, acc[k][3]);
    }
  }
  #pragma unroll
  for (int k=0;k<KK;k++){
    #pragma unroll
    for (int i=0;i<4;i++){
      float v = acc[k][i];
      for (int off=32; off>0; off>>=1) v += __shfl_down(v, off);
      acc[k][i] = v;
    }
  }
  __shared__ float part[4][KK][4];
  int lane = t & 63, wv = t >> 6;
  if (lane == 0){
    #pragma unroll
    for (int k=0;k<KK;k++){ part[wv][k][0]=acc[k][0]; part[wv][k][1]=acc[k][1];
                            part[wv][k][2]=acc[k][2]; part[wv][k][3]=acc[k][3]; }
  }
  __syncthreads();
  if (t < 64){
    int k = t >> 2, i = t & 3;
    float s = part[0][k][i] + part[1][k][i] + part[2][k][i] + part[3][k][i];
    G[((size_t)b*KK + k)*CC + c0 + i] = s;
  }
}

// ---------------- K3: S = softmax_c(G) ; WS = w_beta.S^T packed as MFMA A-frags (K=16 pad 32) ----------------
__global__ __launch_bounds__(256) void k3_smws(
    const float* __restrict__ G, const float* __restrict__ w_beta, u16* __restrict__ wspk)
{
  int b = blockIdx.x, t = threadIdx.x;
  __shared__ float sl[KK][CC];
  for (int k=0;k<KK;k++) sl[k][t] = G[((size_t)b*KK + k)*CC + t];
  __syncthreads();
  int lane = t & 63, wv = t >> 6;
  for (int r=0;r<4;r++){
    int k = wv*4 + r;
    float v0 = sl[k][lane], v1 = sl[k][lane+64], v2 = sl[k][lane+128], v3 = sl[k][lane+192];
    float m = fmaxf(fmaxf(v0,v1), fmaxf(v2,v3));
    for (int off=32; off>0; off>>=1) m = fmaxf(m, __shfl_xor(m, off));
    float e0=__expf(v0-m), e1=__expf(v1-m), e2=__expf(v2-m), e3=__expf(v3-m);
    float s = e0+e1+e2+e3;
    for (int off=32; off>0; off>>=1) s += __shfl_xor(s, off);
    float inv = 1.f/s;
    sl[k][lane]=e0*inv; sl[k][lane+64]=e1*inv; sl[k][lane+128]=e2*inv; sl[k][lane+192]=e3*inv;
  }
  __syncthreads();
  const float* wb = w_beta + (size_t)t*CC;
  float acc[KK];
  #pragma unroll
  for (int k=0;k<KK;k++) acc[k]=0.f;
  for (int c=0;c<CC;c++){
    float w = wb[c];
    #pragma unroll
    for (int k=0;k<KK;k++) acc[k] = fmaf(w, sl[k][c], acc[k]);
  }
  // frag write: A[row=o&15][k] at block ot=o>>4; lanes lk 0,1 hold k0..15; lk 2,3 zero
  int ot = t >> 4, lo = t & 15;
  union { u16 h[8]; uint4 u; } pk;
  #pragma unroll
  for (int lkq=0; lkq<2; lkq++){
    #pragma unroll
    for (int e=0;e<8;e++) pk.h[e] = f2us(acc[lkq*8+e]);
    *reinterpret_cast<uint4*>(wspk + ((size_t)(b*16 + ot)*64 + lkq*16 + lo)*8) = pk.u;
  }
  uint4 z; z.x=z.y=z.z=z.w=0u;
  *reinterpret_cast<uint4*>(wspk + ((size_t)(b*16 + ot)*64 + 2*16 + lo)*8) = z;
  *reinterpret_cast<uint4*>(wspk + ((size_t)(b*16 + ot)*64 + 3*16 + lo)*8) = z;
}

// ---------------- K5: spatial convs -> F4, Cm ----------------
__global__ __launch_bounds__(256) void k5_conv(
    const float* __restrict__ AM, const float* __restrict__ w1, const float* __restrict__ w3,
    const float* __restrict__ w5, const float* __restrict__ w7, const float* __restrict__ wf2c,
    float* __restrict__ F4, float* __restrict__ Cm)
{
  __shared__ float w3l[18], w5l[50], w7l[98], w1l[2], wcl[4];
  int t = threadIdx.x;
  if (t < 2)  w1l[t] = w1[t];
  if (t < 18) w3l[t] = w3[t];
  if (t < 50) w5l[t] = w5[t];
  if (t < 98) w7l[t] = w7[t];
  if (t < 4)  wcl[t] = wf2c[t];
  __syncthreads();
  int gid = blockIdx.x*256 + t;
  int b = gid / NN, n = gid % NN;
  int h = n / HW, w = n % HW;
  const float* am = AM + (size_t)b*2*NN;
  float a0 = am[n], a1 = am[NN + n];
  float s1v = lrelu(a0*w1l[0] + a1*w1l[1]);
  float s3v=0.f, s5v=0.f, s7v=0.f;
  for (int p=-3;p<=3;p++){
    int hh = h + p;
    if (hh < 0 || hh >= HW) continue;
    for (int q=-3;q<=3;q++){
      int ww = w + q;
      if (ww < 0 || ww >= HW) continue;
      float v0 = am[hh*HW+ww], v1 = am[NN + hh*HW + ww];
      s7v += v0*w7l[(p+3)*7 + (q+3)] + v1*w7l[49 + (p+3)*7 + (q+3)];
      if (p>=-2 && p<=2 && q>=-2 && q<=2)
        s5v += v0*w5l[(p+2)*5 + (q+2)] + v1*w5l[25 + (p+2)*5 + (q+2)];
      if (p>=-1 && p<=1 && q>=-1 && q<=1)
        s3v += v0*w3l[(p+1)*3 + (q+1)] + v1*w3l[9 + (p+1)*3 + (q+1)];
    }
  }
  s3v = lrelu(s3v); s5v = lrelu(s5v); s7v = lrelu(s7v);
  float* f4p = F4 + (size_t)b*4*NN + n;
  f4p[0] = s1v; f4p[NN] = s3v; f4p[2*(size_t)NN] = s5v; f4p[3*(size_t)NN] = s7v;
  Cm[(size_t)b*NN + n] = lrelu(s1v*wcl[0] + s3v*wcl[1] + s5v*wcl[2] + s7v*wcl[3]);
}

// ---------------- K6a: T[b,h,k] = sum_w Bm[b,h*96+w]*Cm[b,w*96+k] ----------------
__global__ __launch_bounds__(256) void k6a_t(
    const float* __restrict__ Bm, const float* __restrict__ Cm, float* __restrict__ Tsc)
{
  __shared__ float Cl[NN];
  int b = blockIdx.x, t = threadIdx.x;
  for (int i=t;i<NN;i+=256) Cl[i] = Cm[(size_t)b*NN + i];
  __syncthreads();
  const float* bp = Bm + (size_t)b*NN;
  for (int g=0; g<9; g++){
    int idx4 = (t + 256*g)*4;
    int h = idx4/96, k0 = idx4%96;
    float a0=0.f,a1=0.f,a2=0.f,a3=0.f;
    const float* brow = bp + h*96;
    for (int w2=0;w2<96;w2++){
      float bv = brow[w2];
      float4 cv = *reinterpret_cast<const float4*>(&Cl[w2*96 + k0]);
      a0=fmaf(bv,cv.x,a0); a1=fmaf(bv,cv.y,a1); a2=fmaf(bv,cv.z,a2); a3=fmaf(bv,cv.w,a3);
    }
    float4 o4; o4.x=a0; o4.y=a1; o4.z=a2; o4.w=a3;
    *reinterpret_cast<float4*>(Tsc + (size_t)b*NN + idx4) = o4;
  }
}

// ---------------- K6b: Ssp = softmax_k(T), packed into MFMA A-frag layout ----------------
__global__ __launch_bounds__(256) void k6b_sm(
    const float* __restrict__ Tsc, u16* __restrict__ spk)
{
  int gid = blockIdx.x*256 + threadIdx.x;
  if (gid >= BN*96) return;
  int b = gid/96, h = gid%96;
  const float* row = Tsc + (size_t)b*NN + h*96;
  float m = -3e38f;
  for (int k=0;k<96;k++) m = fmaxf(m, row[k]);
  float s = 0.f;
  for (int k=0;k<96;k++) s += __expf(row[k]-m);
  float inv = 1.f/s;
  int mf = h >> 4;
  for (int g=0; g<12; g++){
    int ks = g >> 2, lk = g & 3;
    union { u16 hh[8]; uint4 u; } pk;
    #pragma unroll
    for (int e=0;e<8;e++) pk.hh[e] = f2us(__expf(row[g*8+e]-m)*inv);
    *reinterpret_cast<uint4*>(spk + ((size_t)(((b*6 + mf)*3 + ks)*64) + lk*16 + (h&15))*8) = pk.u;
  }
}

// ---------------- KW: pack w_h / w_m / w_hm (256x512) and w_e (256x256) into bf16 A-frag order ----------------
__global__ __launch_bounds__(256) void kw_pack(
    const float* __restrict__ w_h, const float* __restrict__ w_m,
    const float* __restrict__ w_hm, const float* __restrict__ w_e,
    u16* __restrict__ wpk, u16* __restrict__ wpkE)
{
  int gid = blockIdx.x*256 + threadIdx.x;   // 57344
  if (gid < 49152){
    int mat = gid >> 14;
    int r = gid & 16383;
    int ot = r >> 10;
    int ks = (r >> 6) & 15;
    int l  = r & 63;
    const float* W = (mat==0) ? w_h : ((mat==1) ? w_m : w_hm);
    int o = ot*16 + (l & 15);
    int c = ks*32 + (l >> 4)*8;
    const float* src = W + (size_t)o*512 + c;
    union { u16 h[8]; uint4 u; } pk;
    #pragma unroll
    for (int e=0;e<8;e++) pk.h[e] = f2us(src[e]);
    *reinterpret_cast<uint4*>(wpk + (size_t)gid*8) = pk.u;
  } else {
    int r = gid - 49152;                    // 8192 frags for w_e (K=256)
    int ot = r >> 9;
    int ks = (r >> 6) & 7;
    int l  = r & 63;
    int o = ot*16 + (l & 15);
    int c = ks*32 + (l >> 4)*8;
    const float* src = w_e + (size_t)o*256 + c;
    union { u16 h[8]; uint4 u; } pk;
    #pragma unroll
    for (int e=0;e<8;e++) pk.h[e] = f2us(src[e]);
    *reinterpret_cast<uint4*>(wpkE + (size_t)r*8) = pk.u;
  }
}

// ---------------- K7M: WD = w_e . lrelu(w_f2d . F4) — MFMA, M=256 N=64 K=256 per block ----------------
__global__ __launch_bounds__(256) void k7m(
    const float* __restrict__ F4, const float* __restrict__ w_f2d,
    const u16* __restrict__ wpkE, u16* __restrict__ WD)
{
  __shared__ uint4 sm4[2048];               // 32 KB: [64 n][256 c] bf16 swizzled
  char* sm = reinterpret_cast<char*>(sm4);
  int t = threadIdx.x;
  int b = blockIdx.x / 144;
  int n0 = (blockIdx.x % 144) * 64;
  int n = t & 63, cg = t >> 6;
  float f0 = F4[((size_t)b*4+0)*NN + n0 + n];
  float f1 = F4[((size_t)b*4+1)*NN + n0 + n];
  float f2 = F4[((size_t)b*4+2)*NN + n0 + n];
  float f3 = F4[((size_t)b*4+3)*NN + n0 + n];
  for (int c8 = 0; c8 < 8; ++c8){
    int c = cg*64 + c8*8;
    union { u16 h[8]; uint4 u; } pk;
    #pragma unroll
    for (int e=0;e<8;e++){
      const float* wfp = w_f2d + (size_t)(c+e)*4;
      pk.h[e] = f2us(lrelu(fmaf(wfp[0],f0, fmaf(wfp[1],f1, fmaf(wfp[2],f2, wfp[3]*f3)))));
    }
    *reinterpret_cast<uint4*>(sm + swz7(n, c)) = pk.u;
  }
  __syncthreads();
  int w = t >> 6, l = t & 63, ln = l & 15, lk = l >> 4;
  f32x4 acc[4][4];
  #pragma unroll
  for (int i=0;i<4;i++){ acc[i][0]=0.f; acc[i][1]=0.f; acc[i][2]=0.f; acc[i][3]=0.f; }
  for (int ks=0; ks<8; ++ks){
    bf16x8 bfr[4];
    #pragma unroll
    for (int nf=0; nf<4; nf++)
      bfr[nf] = *reinterpret_cast<const bf16x8*>(sm + swz7(nf*16 + ln, ks*32 + lk*8));
    #pragma unroll
    for (int mf=0; mf<4; mf++){
      bf16x8 afr = *reinterpret_cast<const bf16x8*>(wpkE + ((size_t)((w*4+mf)*8 + ks)*64 + l)*8);
      #pragma unroll
      for (int nf=0; nf<4; nf++)
        acc[mf][nf] = __builtin_amdgcn_mfma_f32_16x16x32_bf16(afr, bfr[nf], acc[mf][nf], 0,0,0);
    }
  }
  #pragma unroll
  for (int mf=0; mf<4; mf++){
    #pragma unroll
    for (int nf=0; nf<4; nf++){
      #pragma unroll
      for (int r=0;r<4;r++){
        int o = (w*4+mf)*16 + lk*4 + r;
        WD[((size_t)b*CC + o)*NN + n0 + nf*16 + ln] = f2us(acc[mf][nf][r]);
      }
    }
  }
}

// ---------------- K8M: out2 = Ssp x WD + x — MFMA, M=96(h) N=192(2o x 96w) K=96 per block ----------------
__global__ __launch_bounds__(256) void k8m(
    const u16* __restrict__ WD, const u16* __restrict__ spk,
    const float* __restrict__ x, u16* __restrict__ out2)
{
  __shared__ uint4 sm4[3072];               // 48 KB: [192 col][128 k-pad] bf16 swizzled
  char* sm = reinterpret_cast<char*>(sm4);
  int t = threadIdx.x;
  int b = blockIdx.x >> 7;
  int o0 = (blockIdx.x & 127) * 2;
  for (int it=0; it<9; ++it){
    int s = it*256 + t;                     // 0..2303
    int w16 = s % 12;
    int k   = (s / 12) % 96;
    int oi  = s / 1152;
    union { u16 h[8]; uint4 u; } v;
    v.u = *reinterpret_cast<const uint4*>(WD + ((size_t)b*CC + o0+oi)*NN + k*96 + w16*8);
    #pragma unroll
    for (int e=0;e<8;e++){
      int col = oi*96 + w16*8 + e;
      *reinterpret_cast<u16*>(sm + swz8(col, k)) = v.h[e];
    }
  }
  __syncthreads();
  int w = t >> 6, l = t & 63, ln = l & 15, lk = l >> 4;
  f32x4 acc[6][3];
  #pragma unroll
  for (int i=0;i<6;i++){ acc[i][0]=0.f; acc[i][1]=0.f; acc[i][2]=0.f; }
  for (int ks=0; ks<3; ++ks){
    bf16x8 bfr[3];
    #pragma unroll
    for (int j=0;j<3;j++){
      int col = (w*3 + j)*16 + ln;
      bfr[j] = *reinterpret_cast<const bf16x8*>(sm + swz8(col, ks*32 + lk*8));
    }
    #pragma unroll
    for (int mf=0; mf<6; mf++){
      bf16x8 afr = *reinterpret_cast<const bf16x8*>(spk + ((size_t)(((b*6 + mf)*3 + ks)*64) + l)*8);
      #pragma unroll
      for (int j=0;j<3;j++)
        acc[mf][j] = __builtin_amdgcn_mfma_f32_16x16x32_bf16(afr, bfr[j], acc[mf][j], 0,0,0);
    }
  }
  #pragma unroll
  for (int j=0;j<3;j++){
    int col = (w*3 + j)*16 + ln;
    int oi = (col >= 96) ? 1 : 0;
    int ww = col - 96*oi;
    const float* xp = x + ((size_t)b*CC + o0+oi)*NN + ww;
    u16* op = out2 + ((size_t)b*CC + o0+oi)*NN + ww;
    #pragma unroll
    for (int mf=0; mf<6; mf++){
      #pragma unroll
      for (int r=0;r<4;r++){
        int h = mf*16 + lk*4 + r;
        op[(size_t)h*96] = f2us(acc[mf][j][r] + xp[(size_t)h*96]);
      }
    }
  }
}

// ---------------- K910: out1 -> Hh -> M -> H_M fused, per 32-pixel tile ----------------
__global__ __launch_bounds__(256) void k910(
    const u16* __restrict__ o2, const u16* __restrict__ xf,
    const float* __restrict__ F, const u16* __restrict__ wspk,
    const u16* __restrict__ wpkH, const u16* __restrict__ wpkM,
    const u16* __restrict__ wpkHM, float* __restrict__ out)
{
  __shared__ uint4 sm4[2048];   // 32 KB: R_A [0,16K)=o2->M, R_B [16K,32K)=out1->Hh
  char* sm = reinterpret_cast<char*>(sm4);
  int t = threadIdx.x;
  int b = blockIdx.x / 288;
  int tile = blockIdx.x % 288;
  int n0 = tile * 32;
  // stage o2 -> R_A [32 n][256 c] (scatter)
  for (int it=0; it<4; ++it){
    int s = it*256 + t;
    int c = s >> 2, q = s & 3;
    union { u16 h[8]; uint4 u; } v;
    v.u = *reinterpret_cast<const uint4*>(o2 + ((size_t)b*CC + c)*NN + n0 + q*8);
    #pragma unroll
    for (int e=0;e<8;e++)
      *reinterpret_cast<u16*>(sm + swz2(q*8+e, c)) = v.h[e];
  }
  int w = t >> 6, l = t & 63, ln = l & 15, lk = l >> 4;
  // ---- ph0: out1 = WS.F + x (K=16 zero-padded to 32), write to R_B ----
  {
    bf16x8 fb[2];
    #pragma unroll
    for (int nf=0; nf<2; nf++){
      bf16x8 z;
      #pragma unroll
      for (int e=0;e<8;e++) z[e] = 0;
      if (lk < 2){
        #pragma unroll
        for (int e=0;e<8;e++){
          int k = lk*8 + e;
          z[e] = (short)f2us(F[((size_t)b*KK + k)*NN + n0 + nf*16 + ln]);
        }
      }
      fb[nf] = z;
    }
    f32x4 acc1[4][2];
    #pragma unroll
    for (int mf=0; mf<4; mf++){
      bf16x8 afr = *reinterpret_cast<const bf16x8*>(wspk + ((size_t)(b*16 + w*4 + mf)*64 + l)*8);
      f32x4 zz = {0.f,0.f,0.f,0.f};
      acc1[mf][0] = __builtin_amdgcn_mfma_f32_16x16x32_bf16(afr, fb[0], zz, 0,0,0);
      acc1[mf][1] = __builtin_amdgcn_mfma_f32_16x16x32_bf16(afr, fb[1], zz, 0,0,0);
    }
    #pragma unroll
    for (int mf=0; mf<4; mf++){
      #pragma unroll
      for (int nf=0; nf<2; nf++){
        int n = nf*16 + ln;
        int nt = tile*2 + nf;
        int obase = w*64 + mf*16 + lk*4;
        union { u16 h[4]; u64 u; } pk;
        #pragma unroll
        for (int r=0;r<4;r++){
          int o = obase + r;
          u16 xv = xf[(((size_t)(b*576 + nt)*8 + (o>>5))*64 + ((o>>3)&3)*16 + ln)*8 + (o&7)];
          pk.h[r] = f2us(acc1[mf][nf][r] + us2f(xv));
        }
        *reinterpret_cast<u64*>(sm + 16384 + swz2(n, obase)) = pk.u;
      }
    }
  }
  __syncthreads();
  f32x4 acc[4][2];
  // ---- ph1: Hh = lrelu(w_h.[out1; out2]) ----
  #pragma unroll
  for (int i=0;i<4;i++){ acc[i][0] = 0.f; acc[i][1] = 0.f; }
  for (int ks=0; ks<16; ++ks){
    int c = (ks & 7)*32 + lk*8;
    int roff = (ks < 8) ? 16384 : 0;
    bf16x8 bfr0 = *reinterpret_cast<const bf16x8*>(sm + roff + swz2(ln,    c));
    bf16x8 bfr1 = *reinterpret_cast<const bf16x8*>(sm + roff + swz2(16+ln, c));
    #pragma unroll
    for (int mf=0; mf<4; mf++){
      bf16x8 afr = *reinterpret_cast<const bf16x8*>(wpkH + ((size_t)((w*4+mf)*16 + ks)*64 + l)*8);
      acc[mf][0] = __builtin_amdgcn_mfma_f32_16x16x32_bf16(afr, bfr0, acc[mf][0], 0,0,0);
      acc[mf][1] = __builtin_amdgcn_mfma_f32_16x16x32_bf16(afr, bfr1, acc[mf][1], 0,0,0);
    }
  }
  __syncthreads();           // all ph1 reads of R_A/R_B complete
  // Hh -> R_B (overwrite out1)
  #pragma unroll
  for (int mf=0; mf<4; mf++){
    #pragma unroll
    for (int nf=0; nf<2; nf++){
      int n = nf*16 + ln;
      int obase = w*64 + mf*16 + lk*4;
      union { u16 h[4]; u64 u; } pk;
      #pragma unroll
      for (int r=0;r<4;r++) pk.h[r] = f2us(lrelu(acc[mf][nf][r]));
      *reinterpret_cast<u64*>(sm + 16384 + swz2(n, obase)) = pk.u;
    }
  }
  __syncthreads();
  // ---- ph2a: M = sigmoid(w_m.[Hh; x]) ----
  #pragma unroll
  for (int i=0;i<4;i++){ acc[i][0] = 0.f; acc[i][1] = 0.f; }
  for (int ks=0; ks<16; ++ks){
    bf16x8 bfr0, bfr1;
    if (ks < 8){
      int c = ks*32 + lk*8;
      bfr0 = *reinterpret_cast<const bf16x8*>(sm + 16384 + swz2(ln,    c));
      bfr1 = *reinterpret_cast<const bf16x8*>(sm + 16384 + swz2(16+ln, c));
    } else {
      bfr0 = *reinterpret_cast<const bf16x8*>(xf + (((size_t)(b*576 + tile*2  )*8 + (ks-8))*64 + l)*8);
      bfr1 = *reinterpret_cast<const bf16x8*>(xf + (((size_t)(b*576 + tile*2+1)*8 + (ks-8))*64 + l)*8);
    }
    #pragma unroll
    for (int mf=0; mf<4; mf++){
      bf16x8 afr = *reinterpret_cast<const bf16x8*>(wpkM + ((size_t)((w*4+mf)*16 + ks)*64 + l)*8);
      acc[mf][0] = __builtin_amdgcn_mfma_f32_16x16x32_bf16(afr, bfr0, acc[mf][0], 0,0,0);
      acc[mf][1] = __builtin_amdgcn_mfma_f32_16x16x32_bf16(afr, bfr1, acc[mf][1], 0,0,0);
    }
  }
  // M -> R_A (o2 dead since ph1-end barrier)
  #pragma unroll
  for (int mf=0; mf<4; mf++){
    #pragma unroll
    for (int nf=0; nf<2; nf++){
      int n = nf*16 + ln;
      int obase = w*64 + mf*16 + lk*4;
      union { u16 h[4]; u64 u; } pk;
      #pragma unroll
      for (int r=0;r<4;r++) pk.h[r] = f2us(1.f/(1.f + __expf(-acc[mf][nf][r])));
      *reinterpret_cast<u64*>(sm + swz2(n, obase)) = pk.u;
    }
  }
  __syncthreads();
  // ---- ph2b: out = lrelu(w_hm.[Hh; M]) -> fp32 ----
  #pragma unroll
  for (int i=0;i<4;i++){ acc[i][0] = 0.f; acc[i][1] = 0.f; }
  for (int ks=0; ks<16; ++ks){
    int c = (ks & 7)*32 + lk*8;
    int roff = (ks < 8) ? 16384 : 0;
    bf16x8 bfr0 = *reinterpret_cast<const bf16x8*>(sm + roff + swz2(ln,    c));
    bf16x8 bfr1 = *reinterpret_cast<const bf16x8*>(sm + roff + swz2(16+ln, c));
    #pragma unroll
    for (int mf=0; mf<4; mf++){
      bf16x8 afr = *reinterpret_cast<const bf16x8*>(wpkHM + ((size_t)((w*4+mf)*16 + ks)*64 + l)*8);
      acc[mf][0] = __builtin_amdgcn_mfma_f32_16x16x32_bf16(afr, bfr0, acc[mf][0], 0,0,0);
      acc[mf][1] = __builtin_amdgcn_mfma_f32_16x16x32_bf16(afr, bfr1, acc[mf][1], 0,0,0);
    }
  }
  #pragma unroll
  for (int mf=0; mf<4; mf++){
    #pragma unroll
    for (int nf=0; nf<2; nf++){
      #pragma unroll
      for (int r=0;r<4;r++){
        int o = w*64 + mf*16 + lk*4 + r;
        out[((size_t)b*CC + o)*NN + n0 + nf*16 + ln] = lrelu(acc[mf][nf][r]);
      }
    }
  }
}

extern "C" void kernel_launch(void* const* d_in, const int* in_sizes, int n_in,
                              void* d_out, int out_size, void* d_ws, size_t ws_size,
                              hipStream_t stream)
{
  const float* x     = (const float*)d_in[0];
  const float* w_f   = (const float*)d_in[1];
  const float* w_beta= (const float*)d_in[2];
  const float* w1    = (const float*)d_in[3];
  const float* w3    = (const float*)d_in[4];
  const float* w5    = (const float*)d_in[5];
  const float* w7    = (const float*)d_in[6];
  const float* w_a2b = (const float*)d_in[7];
  const float* w_f2c = (const float*)d_in[8];
  const float* w_f2d = (const float*)d_in[9];
  const float* w_e   = (const float*)d_in[10];
  const float* w_h   = (const float*)d_in[11];
  const float* w_m   = (const float*)d_in[12];
  const float* w_hm  = (const float*)d_in[13];

  char* ws = (char*)d_ws;
  size_t off = 0;
  auto alloc = [&](size_t bytes) -> void* {
    void* p = ws + off; off += (bytes + 255) & ~(size_t)255; return p;
  };
  float* F    = (float*)alloc(sizeof(float)*(size_t)BN*KK*NN);
  float* AMb  = (float*)alloc(sizeof(float)*(size_t)BN*2*NN);
  float* Bmv  = (float*)alloc(sizeof(float)*(size_t)BN*NN);
  float* Cmv  = (float*)alloc(sizeof(float)*(size_t)BN*NN);
  float* F4   = (float*)alloc(sizeof(float)*(size_t)BN*4*NN);
  float* G    = (float*)alloc(sizeof(float)*(size_t)BN*KK*CC);
  float* Tsc  = (float*)alloc(sizeof(float)*(size_t)BN*NN);
  u16*   spk  = (u16*)alloc(sizeof(u16)*(size_t)BN*NN);           // packed softmax S
  u16*   WD   = (u16*)alloc(sizeof(u16)*(size_t)BN*CC*NN);
  u16*   o2   = (u16*)alloc(sizeof(u16)*(size_t)BN*CC*NN);
  u16*   xf   = (u16*)alloc(sizeof(u16)*(size_t)BN*CC*NN);        // x bf16 B-frag layout
  u16*   wpk  = (u16*)alloc(sizeof(u16)*(size_t)3*16384*8);       // packed w_h/w_m/w_hm
  u16*   wpkE = (u16*)alloc(sizeof(u16)*(size_t)8192*8);          // packed w_e
  u16*   wspk = (u16*)alloc(sizeof(u16)*(size_t)BN*16*64*8);      // packed WS A-frags
  (void)ws_size; (void)in_sizes; (void)n_in; (void)out_size;

  u16* wpkH  = wpk;
  u16* wpkM  = wpk + (size_t)16384*8;
  u16* wpkHM = wpk + (size_t)2*16384*8;

  kw_pack <<<224, 256, 0, stream>>>(w_h, w_m, w_hm, w_e, wpk, wpkE);
  k1_fx   <<<288, 256, 0, stream>>>(x, w_f, w_a2b, F, AMb, Bmv, xf);
  k2_g    <<<512, 256, 0, stream>>>(x, F, G);
  k3_smws <<<8,   256, 0, stream>>>(G, w_beta, wspk);
  k5_conv <<<288, 256, 0, stream>>>(AMb, w1, w3, w5, w7, w_f2c, F4, Cmv);
  k6a_t   <<<8,   256, 0, stream>>>(Bmv, Cmv, Tsc);
  k6b_sm  <<<3,   256, 0, stream>>>(Tsc, spk);
  k7m     <<<1152,256, 0, stream>>>(F4, w_f2d, wpkE, WD);
  k8m     <<<1024,256, 0, stream>>>(WD, spk, x, o2);
  k910    <<<2304,256, 0, stream>>>(o2, xf, F, wspk, wpkH, wpkM, wpkHM, (float*)d_out);
}

// Round 7
// 382.072 us; speedup vs baseline: 5.4214x; 1.1396x over previous
//
#include <hip/hip_runtime.h>

typedef unsigned short u16;
typedef unsigned int   u32;
typedef unsigned long long u64;

#define BN 8
#define CC 256
#define HW 96
#define NN 9216   // 96*96
#define KK 16

typedef __attribute__((ext_vector_type(8))) short bf16x8;
typedef __attribute__((ext_vector_type(4))) float f32x4;

__device__ __forceinline__ float us2f(u16 u){
  union { u32 i; float f; } v; v.i = ((u32)u) << 16; return v.f;
}
__device__ __forceinline__ u16 f2us(float f){
  union { float f; u32 i; } v; v.f = f;
  u32 x = v.i;
  u32 r = (x + 0x7fffu + ((x >> 16) & 1u)) >> 16;  // RNE
  return (u16)r;
}
__device__ __forceinline__ float lrelu(float v){ return v >= 0.f ? v : 0.001f*v; }

// LDS swizzle for [64 n][256 c] bf16 tile (512B rows), 16B granules
__device__ __forceinline__ u32 swz7(int n, int c){
  return (u32)(n*512 + ((((c>>3) ^ (n&31)) & 31)<<4) + ((c&7)<<1));
}
// LDS swizzle for [192 col][96 k] bf16 tile padded to 256B rows
__device__ __forceinline__ u32 swz8(int col, int k){
  return (u32)(col*256 + ((((k>>3) ^ (col&15)) & 15)<<4) + ((k&7)<<1));
}

// ---------------- K1: F = w_f.x ; Bm = lrelu(w_a2b.x) ; AM = [mean,max] ; xf = x bf16 B-frags ----------------
__global__ __launch_bounds__(256) void k1_fx(
    const float* __restrict__ x, const float* __restrict__ w_f, const float* __restrict__ w_a2b,
    float* __restrict__ F, float* __restrict__ AM, float* __restrict__ Bm, u16* __restrict__ xf)
{
  __shared__ float wf[CC][KK];   // [c][k]
  __shared__ float wa[CC];
  int t = threadIdx.x;
  for (int i = t; i < KK*CC; i += 256) wf[i & 255][i >> 8] = w_f[i];
  wa[t] = w_a2b[t];
  __syncthreads();
  int pid = blockIdx.x*256 + t;             // 1 pixel per thread, 288 blocks
  int b = pid / NN;
  int n = pid % NN;
  const float* xp = x + (size_t)b*CC*NN + n;
  float a0[KK];
  #pragma unroll
  for (int k=0;k<KK;k++) a0[k]=0.f;
  float s0=0.f, m0=-3e38f, b0=0.f;
  int nt = n >> 4, lnn = n & 15;
  u16* xfb = xf + ((size_t)(b*576 + nt)*8)*512;   // ks*512 + lane*8 + e  (u16 units)
  union { u16 h[8]; uint4 u; } pk;
  for (int c=0;c<CC;c++){
    float v = xp[(size_t)c*NN];
    s0 += v;
    m0 = fmaxf(m0, v);
    b0 = fmaf(wa[c], v, b0);
    const float* wr = wf[c];
    #pragma unroll
    for (int k=0;k<KK;k++) a0[k] = fmaf(wr[k], v, a0[k]);
    pk.h[c & 7] = f2us(v);
    if ((c & 7) == 7){
      int ks = c >> 5, lkq = (c >> 3) & 3;
      *reinterpret_cast<uint4*>(xfb + ((size_t)ks*64 + lkq*16 + lnn)*8) = pk.u;
    }
  }
  float* Fp = F + (size_t)b*KK*NN + n;
  #pragma unroll
  for (int k=0;k<KK;k++) Fp[(size_t)k*NN] = a0[k];
  AM[(size_t)b*2*NN + n] = s0*(1.f/256.f);
  AM[(size_t)b*2*NN + NN + n] = m0;
  Bm[(size_t)b*NN + n] = lrelu(b0);
}

// ---------------- K2: G[b,k,c] = sum_n F[b,k,n]*x[b,c,n]  (4 c per block) ----------------
__global__ __launch_bounds__(256) void k2_g(
    const float* __restrict__ x, const float* __restrict__ F, float* __restrict__ G)
{
  int b = blockIdx.x >> 6;
  int c0 = (blockIdx.x & 63) * 4;
  int t = threadIdx.x;
  const float* Fp = F + (size_t)b*KK*NN;
  const float* xp = x + ((size_t)b*CC + c0)*NN;
  float acc[KK][4];
  #pragma unroll
  for (int k=0;k<KK;k++){ acc[k][0]=acc[k][1]=acc[k][2]=acc[k][3]=0.f; }
  for (int n = t; n < NN; n += 256){
    float xv0 = xp[n];
    float xv1 = xp[(size_t)NN + n];
    float xv2 = xp[(size_t)2*NN + n];
    float xv3 = xp[(size_t)3*NN + n];
    #pragma unroll
    for (int k=0;k<KK;k++){
      float fv = Fp[(size_t)k*NN + n];
      acc[k][0] = fmaf(fv, xv0, acc[k][0]);
      acc[k][1] = fmaf(fv, xv1, acc[k][1]);
      acc[k][2] = fmaf(fv, xv2, acc[k][2]);
      acc[k][3] = fmaf(fv, xv3, acc[k][3]);
    }
  }
  #pragma unroll
  for (int k=0;k<KK;k++){
    #pragma unroll
    for (int i=0;i<4;i++){
      float v = acc[k][i];
      for (int off=32; off>0; off>>=1) v += __shfl_down(v, off);
      acc[k][i] = v;
    }
  }
  __shared__ float part[4][KK][4];
  int lane = t & 63, wv = t >> 6;
  if (lane == 0){
    #pragma unroll
    for (int k=0;k<KK;k++){ part[wv][k][0]=acc[k][0]; part[wv][k][1]=acc[k][1];
                            part[wv][k][2]=acc[k][2]; part[wv][k][3]=acc[k][3]; }
  }
  __syncthreads();
  if (t < 64){
    int k = t >> 2, i = t & 3;
    float s = part[0][k][i] + part[1][k][i] + part[2][k][i] + part[3][k][i];
    G[((size_t)b*KK + k)*CC + c0 + i] = s;
  }
}

// ---------------- K3: S = softmax_c(G) ; WS = w_beta.S^T packed as MFMA A-frags (K=16 pad 32) ----------------
__global__ __launch_bounds__(256) void k3_smws(
    const float* __restrict__ G, const float* __restrict__ w_beta, u16* __restrict__ wspk)
{
  int b = blockIdx.x, t = threadIdx.x;
  __shared__ float sl[KK][CC];
  for (int k=0;k<KK;k++) sl[k][t] = G[((size_t)b*KK + k)*CC + t];
  __syncthreads();
  int lane = t & 63, wv = t >> 6;
  for (int r=0;r<4;r++){
    int k = wv*4 + r;
    float v0 = sl[k][lane], v1 = sl[k][lane+64], v2 = sl[k][lane+128], v3 = sl[k][lane+192];
    float m = fmaxf(fmaxf(v0,v1), fmaxf(v2,v3));
    for (int off=32; off>0; off>>=1) m = fmaxf(m, __shfl_xor(m, off));
    float e0=__expf(v0-m), e1=__expf(v1-m), e2=__expf(v2-m), e3=__expf(v3-m);
    float s = e0+e1+e2+e3;
    for (int off=32; off>0; off>>=1) s += __shfl_xor(s, off);
    float inv = 1.f/s;
    sl[k][lane]=e0*inv; sl[k][lane+64]=e1*inv; sl[k][lane+128]=e2*inv; sl[k][lane+192]=e3*inv;
  }
  __syncthreads();
  const float* wb = w_beta + (size_t)t*CC;
  float acc[KK];
  #pragma unroll
  for (int k=0;k<KK;k++) acc[k]=0.f;
  for (int c=0;c<CC;c++){
    float w = wb[c];
    #pragma unroll
    for (int k=0;k<KK;k++) acc[k] = fmaf(w, sl[k][c], acc[k]);
  }
  int ot = t >> 4, lo = t & 15;
  union { u16 h[8]; uint4 u; } pk;
  #pragma unroll
  for (int lkq=0; lkq<2; lkq++){
    #pragma unroll
    for (int e=0;e<8;e++) pk.h[e] = f2us(acc[lkq*8+e]);
    *reinterpret_cast<uint4*>(wspk + ((size_t)(b*16 + ot)*64 + lkq*16 + lo)*8) = pk.u;
  }
  uint4 z; z.x=z.y=z.z=z.w=0u;
  *reinterpret_cast<uint4*>(wspk + ((size_t)(b*16 + ot)*64 + 2*16 + lo)*8) = z;
  *reinterpret_cast<uint4*>(wspk + ((size_t)(b*16 + ot)*64 + 3*16 + lo)*8) = z;
}

// ---------------- K5: spatial convs -> F4, Cm ----------------
__global__ __launch_bounds__(256) void k5_conv(
    const float* __restrict__ AM, const float* __restrict__ w1, const float* __restrict__ w3,
    const float* __restrict__ w5, const float* __restrict__ w7, const float* __restrict__ wf2c,
    float* __restrict__ F4, float* __restrict__ Cm)
{
  __shared__ float w3l[18], w5l[50], w7l[98], w1l[2], wcl[4];
  int t = threadIdx.x;
  if (t < 2)  w1l[t] = w1[t];
  if (t < 18) w3l[t] = w3[t];
  if (t < 50) w5l[t] = w5[t];
  if (t < 98) w7l[t] = w7[t];
  if (t < 4)  wcl[t] = wf2c[t];
  __syncthreads();
  int gid = blockIdx.x*256 + t;
  int b = gid / NN, n = gid % NN;
  int h = n / HW, w = n % HW;
  const float* am = AM + (size_t)b*2*NN;
  float a0 = am[n], a1 = am[NN + n];
  float s1v = lrelu(a0*w1l[0] + a1*w1l[1]);
  float s3v=0.f, s5v=0.f, s7v=0.f;
  for (int p=-3;p<=3;p++){
    int hh = h + p;
    if (hh < 0 || hh >= HW) continue;
    for (int q=-3;q<=3;q++){
      int ww = w + q;
      if (ww < 0 || ww >= HW) continue;
      float v0 = am[hh*HW+ww], v1 = am[NN + hh*HW + ww];
      s7v += v0*w7l[(p+3)*7 + (q+3)] + v1*w7l[49 + (p+3)*7 + (q+3)];
      if (p>=-2 && p<=2 && q>=-2 && q<=2)
        s5v += v0*w5l[(p+2)*5 + (q+2)] + v1*w5l[25 + (p+2)*5 + (q+2)];
      if (p>=-1 && p<=1 && q>=-1 && q<=1)
        s3v += v0*w3l[(p+1)*3 + (q+1)] + v1*w3l[9 + (p+1)*3 + (q+1)];
    }
  }
  s3v = lrelu(s3v); s5v = lrelu(s5v); s7v = lrelu(s7v);
  float* f4p = F4 + (size_t)b*4*NN + n;
  f4p[0] = s1v; f4p[NN] = s3v; f4p[2*(size_t)NN] = s5v; f4p[3*(size_t)NN] = s7v;
  Cm[(size_t)b*NN + n] = lrelu(s1v*wcl[0] + s3v*wcl[1] + s5v*wcl[2] + s7v*wcl[3]);
}

// ---------------- K6a: T[b,h,k] = sum_w Bm[b,h*96+w]*Cm[b,w*96+k] ----------------
__global__ __launch_bounds__(256) void k6a_t(
    const float* __restrict__ Bm, const float* __restrict__ Cm, float* __restrict__ Tsc)
{
  __shared__ float Cl[NN];
  int b = blockIdx.x, t = threadIdx.x;
  for (int i=t;i<NN;i+=256) Cl[i] = Cm[(size_t)b*NN + i];
  __syncthreads();
  const float* bp = Bm + (size_t)b*NN;
  for (int g=0; g<9; g++){
    int idx4 = (t + 256*g)*4;
    int h = idx4/96, k0 = idx4%96;
    float a0=0.f,a1=0.f,a2=0.f,a3=0.f;
    const float* brow = bp + h*96;
    for (int w2=0;w2<96;w2++){
      float bv = brow[w2];
      float4 cv = *reinterpret_cast<const float4*>(&Cl[w2*96 + k0]);
      a0=fmaf(bv,cv.x,a0); a1=fmaf(bv,cv.y,a1); a2=fmaf(bv,cv.z,a2); a3=fmaf(bv,cv.w,a3);
    }
    float4 o4; o4.x=a0; o4.y=a1; o4.z=a2; o4.w=a3;
    *reinterpret_cast<float4*>(Tsc + (size_t)b*NN + idx4) = o4;
  }
}

// ---------------- K6b: Ssp = softmax_k(T), packed into MFMA A-frag layout ----------------
__global__ __launch_bounds__(256) void k6b_sm(
    const float* __restrict__ Tsc, u16* __restrict__ spk)
{
  int gid = blockIdx.x*256 + threadIdx.x;
  if (gid >= BN*96) return;
  int b = gid/96, h = gid%96;
  const float* row = Tsc + (size_t)b*NN + h*96;
  float m = -3e38f;
  for (int k=0;k<96;k++) m = fmaxf(m, row[k]);
  float s = 0.f;
  for (int k=0;k<96;k++) s += __expf(row[k]-m);
  float inv = 1.f/s;
  int mf = h >> 4;
  for (int g=0; g<12; g++){
    int ks = g >> 2, lk = g & 3;
    union { u16 hh[8]; uint4 u; } pk;
    #pragma unroll
    for (int e=0;e<8;e++) pk.hh[e] = f2us(__expf(row[g*8+e]-m)*inv);
    *reinterpret_cast<uint4*>(spk + ((size_t)(((b*6 + mf)*3 + ks)*64) + lk*16 + (h&15))*8) = pk.u;
  }
}

// ---------------- KW: pack w_h / w_m / w_hm (256x512) and w_e (256x256) into bf16 A-frag order ----------------
__global__ __launch_bounds__(256) void kw_pack(
    const float* __restrict__ w_h, const float* __restrict__ w_m,
    const float* __restrict__ w_hm, const float* __restrict__ w_e,
    u16* __restrict__ wpk, u16* __restrict__ wpkE)
{
  int gid = blockIdx.x*256 + threadIdx.x;   // 57344
  if (gid < 49152){
    int mat = gid >> 14;
    int r = gid & 16383;
    int ot = r >> 10;
    int ks = (r >> 6) & 15;
    int l  = r & 63;
    const float* W = (mat==0) ? w_h : ((mat==1) ? w_m : w_hm);
    int o = ot*16 + (l & 15);
    int c = ks*32 + (l >> 4)*8;
    const float* src = W + (size_t)o*512 + c;
    union { u16 h[8]; uint4 u; } pk;
    #pragma unroll
    for (int e=0;e<8;e++) pk.h[e] = f2us(src[e]);
    *reinterpret_cast<uint4*>(wpk + (size_t)gid*8) = pk.u;
  } else {
    int r = gid - 49152;                    // 8192 frags for w_e (K=256)
    int ot = r >> 9;
    int ks = (r >> 6) & 7;
    int l  = r & 63;
    int o = ot*16 + (l & 15);
    int c = ks*32 + (l >> 4)*8;
    const float* src = w_e + (size_t)o*256 + c;
    union { u16 h[8]; uint4 u; } pk;
    #pragma unroll
    for (int e=0;e<8;e++) pk.h[e] = f2us(src[e]);
    *reinterpret_cast<uint4*>(wpkE + (size_t)r*8) = pk.u;
  }
}

// ---------------- K7M: WD = w_e . lrelu(w_f2d . F4) — MFMA, M=256 N=64 K=256 per block ----------------
__global__ __launch_bounds__(256) void k7m(
    const float* __restrict__ F4, const float* __restrict__ w_f2d,
    const u16* __restrict__ wpkE, u16* __restrict__ WD)
{
  __shared__ uint4 sm4[2048];               // 32 KB: [64 n][256 c] bf16 swizzled
  char* sm = reinterpret_cast<char*>(sm4);
  int t = threadIdx.x;
  int b = blockIdx.x / 144;
  int n0 = (blockIdx.x % 144) * 64;
  int n = t & 63, cg = t >> 6;
  float f0 = F4[((size_t)b*4+0)*NN + n0 + n];
  float f1 = F4[((size_t)b*4+1)*NN + n0 + n];
  float f2 = F4[((size_t)b*4+2)*NN + n0 + n];
  float f3 = F4[((size_t)b*4+3)*NN + n0 + n];
  for (int c8 = 0; c8 < 8; ++c8){
    int c = cg*64 + c8*8;
    union { u16 h[8]; uint4 u; } pk;
    #pragma unroll
    for (int e=0;e<8;e++){
      const float* wfp = w_f2d + (size_t)(c+e)*4;
      pk.h[e] = f2us(lrelu(fmaf(wfp[0],f0, fmaf(wfp[1],f1, fmaf(wfp[2],f2, wfp[3]*f3)))));
    }
    *reinterpret_cast<uint4*>(sm + swz7(n, c)) = pk.u;
  }
  __syncthreads();
  int w = t >> 6, l = t & 63, ln = l & 15, lk = l >> 4;
  f32x4 acc[4][4];
  #pragma unroll
  for (int i=0;i<4;i++){ acc[i][0]=0.f; acc[i][1]=0.f; acc[i][2]=0.f; acc[i][3]=0.f; }
  for (int ks=0; ks<8; ++ks){
    bf16x8 bfr[4];
    #pragma unroll
    for (int nf=0; nf<4; nf++)
      bfr[nf] = *reinterpret_cast<const bf16x8*>(sm + swz7(nf*16 + ln, ks*32 + lk*8));
    #pragma unroll
    for (int mf=0; mf<4; mf++){
      bf16x8 afr = *reinterpret_cast<const bf16x8*>(wpkE + ((size_t)((w*4+mf)*8 + ks)*64 + l)*8);
      #pragma unroll
      for (int nf=0; nf<4; nf++)
        acc[mf][nf] = __builtin_amdgcn_mfma_f32_16x16x32_bf16(afr, bfr[nf], acc[mf][nf], 0,0,0);
    }
  }
  #pragma unroll
  for (int mf=0; mf<4; mf++){
    #pragma unroll
    for (int nf=0; nf<4; nf++){
      #pragma unroll
      for (int r=0;r<4;r++){
        int o = (w*4+mf)*16 + lk*4 + r;
        WD[((size_t)b*CC + o)*NN + n0 + nf*16 + ln] = f2us(acc[mf][nf][r]);
      }
    }
  }
}

// ---------------- K8M: out2 = Ssp x WD + x — MFMA, M=96(h) N=192(2o x 96w) K=96 per block ----------------
__global__ __launch_bounds__(256) void k8m(
    const u16* __restrict__ WD, const u16* __restrict__ spk,
    const float* __restrict__ x, u16* __restrict__ out2)
{
  __shared__ uint4 sm4[3072];               // 48 KB: [192 col][128 k-pad] bf16 swizzled
  char* sm = reinterpret_cast<char*>(sm4);
  int t = threadIdx.x;
  int b = blockIdx.x >> 7;
  int o0 = (blockIdx.x & 127) * 2;
  for (int it=0; it<9; ++it){
    int s = it*256 + t;                     // 0..2303
    int w16 = s % 12;
    int k   = (s / 12) % 96;
    int oi  = s / 1152;
    union { u16 h[8]; uint4 u; } v;
    v.u = *reinterpret_cast<const uint4*>(WD + ((size_t)b*CC + o0+oi)*NN + k*96 + w16*8);
    #pragma unroll
    for (int e=0;e<8;e++){
      int col = oi*96 + w16*8 + e;
      *reinterpret_cast<u16*>(sm + swz8(col, k)) = v.h[e];
    }
  }
  __syncthreads();
  int w = t >> 6, l = t & 63, ln = l & 15, lk = l >> 4;
  f32x4 acc[6][3];
  #pragma unroll
  for (int i=0;i<6;i++){ acc[i][0]=0.f; acc[i][1]=0.f; acc[i][2]=0.f; }
  for (int ks=0; ks<3; ++ks){
    bf16x8 bfr[3];
    #pragma unroll
    for (int j=0;j<3;j++){
      int col = (w*3 + j)*16 + ln;
      bfr[j] = *reinterpret_cast<const bf16x8*>(sm + swz8(col, ks*32 + lk*8));
    }
    #pragma unroll
    for (int mf=0; mf<6; mf++){
      bf16x8 afr = *reinterpret_cast<const bf16x8*>(spk + ((size_t)(((b*6 + mf)*3 + ks)*64) + l)*8);
      #pragma unroll
      for (int j=0;j<3;j++)
        acc[mf][j] = __builtin_amdgcn_mfma_f32_16x16x32_bf16(afr, bfr[j], acc[mf][j], 0,0,0);
    }
  }
  #pragma unroll
  for (int j=0;j<3;j++){
    int col = (w*3 + j)*16 + ln;
    int oi = (col >= 96) ? 1 : 0;
    int ww = col - 96*oi;
    const float* xp = x + ((size_t)b*CC + o0+oi)*NN + ww;
    u16* op = out2 + ((size_t)b*CC + o0+oi)*NN + ww;
    #pragma unroll
    for (int mf=0; mf<6; mf++){
      #pragma unroll
      for (int r=0;r<4;r++){
        int h = mf*16 + lk*4 + r;
        op[(size_t)h*96] = f2us(acc[mf][j][r] + xp[(size_t)h*96]);
      }
    }
  }
}

// ---------------- K910: out1 -> Hh -> M -> H_M fused, per 64-pixel tile ----------------
__global__ __launch_bounds__(256) void k910(
    const u16* __restrict__ o2, const u16* __restrict__ xf,
    const float* __restrict__ F, const u16* __restrict__ wspk,
    const u16* __restrict__ wpkH, const u16* __restrict__ wpkM,
    const u16* __restrict__ wpkHM, float* __restrict__ out)
{
  __shared__ uint4 sm4[4096];   // 64 KB: R_A [0,32K)=o2->M, R_B [32K,64K)=out1->Hh
  char* sm = reinterpret_cast<char*>(sm4);
  int t = threadIdx.x;
  int b = blockIdx.x / 144;
  int tile = blockIdx.x % 144;
  int n0 = tile * 64;
  // stage o2 -> R_A [64 n][256 c] (scatter)
  for (int it=0; it<8; ++it){
    int s = it*256 + t;
    int c = s >> 3, q = s & 7;
    union { u16 h[8]; uint4 u; } v;
    v.u = *reinterpret_cast<const uint4*>(o2 + ((size_t)b*CC + c)*NN + n0 + q*8);
    #pragma unroll
    for (int e=0;e<8;e++)
      *reinterpret_cast<u16*>(sm + swz7(q*8+e, c)) = v.h[e];
  }
  int w = t >> 6, l = t & 63, ln = l & 15, lk = l >> 4;
  // ---- ph0: out1 = WS.F + x (K=16 zero-padded to 32), write to R_B ----
  {
    bf16x8 fb[4];
    #pragma unroll
    for (int nf=0; nf<4; nf++){
      bf16x8 z;
      #pragma unroll
      for (int e=0;e<8;e++) z[e] = 0;
      if (lk < 2){
        #pragma unroll
        for (int e=0;e<8;e++){
          int k = lk*8 + e;
          z[e] = (short)f2us(F[((size_t)b*KK + k)*NN + n0 + nf*16 + ln]);
        }
      }
      fb[nf] = z;
    }
    #pragma unroll
    for (int mf=0; mf<4; mf++){
      bf16x8 afr = *reinterpret_cast<const bf16x8*>(wspk + ((size_t)(b*16 + w*4 + mf)*64 + l)*8);
      int obase = w*64 + mf*16 + lk*4;
      #pragma unroll
      for (int nf=0; nf<4; nf++){
        f32x4 zz = {0.f,0.f,0.f,0.f};
        f32x4 a1 = __builtin_amdgcn_mfma_f32_16x16x32_bf16(afr, fb[nf], zz, 0,0,0);
        int n = nf*16 + ln;
        int nt = tile*4 + nf;
        // x residual: 4 consecutive o = 4 contiguous u16 in xf (8B aligned)
        u64 xv4 = *reinterpret_cast<const u64*>(
            xf + (((size_t)(b*576 + nt)*8 + (obase>>5))*64 + ((obase>>3)&3)*16 + ln)*8 + (obase&7));
        union { u16 h[4]; u64 u; } pk;
        #pragma unroll
        for (int r=0;r<4;r++)
          pk.h[r] = f2us(a1[r] + us2f((u16)(xv4 >> (16*r))));
        *reinterpret_cast<u64*>(sm + 32768 + swz7(n, obase)) = pk.u;
      }
    }
  }
  __syncthreads();
  f32x4 acc[4][4];
  // ---- ph1: Hh = lrelu(w_h.[out1; out2]) ----
  #pragma unroll
  for (int i=0;i<4;i++){ acc[i][0]=0.f; acc[i][1]=0.f; acc[i][2]=0.f; acc[i][3]=0.f; }
  for (int ks=0; ks<16; ++ks){
    int c = (ks & 7)*32 + lk*8;
    int roff = (ks < 8) ? 32768 : 0;
    bf16x8 bfr[4];
    #pragma unroll
    for (int nf=0; nf<4; nf++)
      bfr[nf] = *reinterpret_cast<const bf16x8*>(sm + roff + swz7(nf*16 + ln, c));
    #pragma unroll
    for (int mf=0; mf<4; mf++){
      bf16x8 afr = *reinterpret_cast<const bf16x8*>(wpkH + ((size_t)((w*4+mf)*16 + ks)*64 + l)*8);
      #pragma unroll
      for (int nf=0; nf<4; nf++)
        acc[mf][nf] = __builtin_amdgcn_mfma_f32_16x16x32_bf16(afr, bfr[nf], acc[mf][nf], 0,0,0);
    }
  }
  __syncthreads();           // all ph1 reads of R_A/R_B complete
  // Hh -> R_B (overwrite out1)
  #pragma unroll
  for (int mf=0; mf<4; mf++){
    int obase = w*64 + mf*16 + lk*4;
    #pragma unroll
    for (int nf=0; nf<4; nf++){
      int n = nf*16 + ln;
      union { u16 h[4]; u64 u; } pk;
      #pragma unroll
      for (int r=0;r<4;r++) pk.h[r] = f2us(lrelu(acc[mf][nf][r]));
      *reinterpret_cast<u64*>(sm + 32768 + swz7(n, obase)) = pk.u;
    }
  }
  __syncthreads();
  // ---- ph2a: M = sigmoid(w_m.[Hh; x]) ----
  #pragma unroll
  for (int i=0;i<4;i++){ acc[i][0]=0.f; acc[i][1]=0.f; acc[i][2]=0.f; acc[i][3]=0.f; }
  for (int ks=0; ks<16; ++ks){
    bf16x8 bfr[4];
    if (ks < 8){
      int c = ks*32 + lk*8;
      #pragma unroll
      for (int nf=0; nf<4; nf++)
        bfr[nf] = *reinterpret_cast<const bf16x8*>(sm + 32768 + swz7(nf*16 + ln, c));
    } else {
      #pragma unroll
      for (int nf=0; nf<4; nf++)
        bfr[nf] = *reinterpret_cast<const bf16x8*>(xf + (((size_t)(b*576 + tile*4 + nf)*8 + (ks-8))*64 + l)*8);
    }
    #pragma unroll
    for (int mf=0; mf<4; mf++){
      bf16x8 afr = *reinterpret_cast<const bf16x8*>(wpkM + ((size_t)((w*4+mf)*16 + ks)*64 + l)*8);
      #pragma unroll
      for (int nf=0; nf<4; nf++)
        acc[mf][nf] = __builtin_amdgcn_mfma_f32_16x16x32_bf16(afr, bfr[nf], acc[mf][nf], 0,0,0);
    }
  }
  // M -> R_A (o2 dead since ph1-end barrier)
  #pragma unroll
  for (int mf=0; mf<4; mf++){
    int obase = w*64 + mf*16 + lk*4;
    #pragma unroll
    for (int nf=0; nf<4; nf++){
      int n = nf*16 + ln;
      union { u16 h[4]; u64 u; } pk;
      #pragma unroll
      for (int r=0;r<4;r++) pk.h[r] = f2us(1.f/(1.f + __expf(-acc[mf][nf][r])));
      *reinterpret_cast<u64*>(sm + swz7(n, obase)) = pk.u;
    }
  }
  __syncthreads();
  // ---- ph2b: out = lrelu(w_hm.[Hh; M]) -> fp32 ----
  #pragma unroll
  for (int i=0;i<4;i++){ acc[i][0]=0.f; acc[i][1]=0.f; acc[i][2]=0.f; acc[i][3]=0.f; }
  for (int ks=0; ks<16; ++ks){
    int c = (ks & 7)*32 + lk*8;
    int roff = (ks < 8) ? 32768 : 0;
    bf16x8 bfr[4];
    #pragma unroll
    for (int nf=0; nf<4; nf++)
      bfr[nf] = *reinterpret_cast<const bf16x8*>(sm + roff + swz7(nf*16 + ln, c));
    #pragma unroll
    for (int mf=0; mf<4; mf++){
      bf16x8 afr = *reinterpret_cast<const bf16x8*>(wpkHM + ((size_t)((w*4+mf)*16 + ks)*64 + l)*8);
      #pragma unroll
      for (int nf=0; nf<4; nf++)
        acc[mf][nf] = __builtin_amdgcn_mfma_f32_16x16x32_bf16(afr, bfr[nf], acc[mf][nf], 0,0,0);
    }
  }
  #pragma unroll
  for (int mf=0; mf<4; mf++){
    #pragma unroll
    for (int nf=0; nf<4; nf++){
      #pragma unroll
      for (int r=0;r<4;r++){
        int o = w*64 + mf*16 + lk*4 + r;
        out[((size_t)b*CC + o)*NN + n0 + nf*16 + ln] = lrelu(acc[mf][nf][r]);
      }
    }
  }
}

extern "C" void kernel_launch(void* const* d_in, const int* in_sizes, int n_in,
                              void* d_out, int out_size, void* d_ws, size_t ws_size,
                              hipStream_t stream)
{
  const float* x     = (const float*)d_in[0];
  const float* w_f   = (const float*)d_in[1];
  const float* w_beta= (const float*)d_in[2];
  const float* w1    = (const float*)d_in[3];
  const float* w3    = (const float*)d_in[4];
  const float* w5    = (const float*)d_in[5];
  const float* w7    = (const float*)d_in[6];
  const float* w_a2b = (const float*)d_in[7];
  const float* w_f2c = (const float*)d_in[8];
  const float* w_f2d = (const float*)d_in[9];
  const float* w_e   = (const float*)d_in[10];
  const float* w_h   = (const float*)d_in[11];
  const float* w_m   = (const float*)d_in[12];
  const float* w_hm  = (const float*)d_in[13];

  char* ws = (char*)d_ws;
  size_t off = 0;
  auto alloc = [&](size_t bytes) -> void* {
    void* p = ws + off; off += (bytes + 255) & ~(size_t)255; return p;
  };
  float* F    = (float*)alloc(sizeof(float)*(size_t)BN*KK*NN);
  float* AMb  = (float*)alloc(sizeof(float)*(size_t)BN*2*NN);
  float* Bmv  = (float*)alloc(sizeof(float)*(size_t)BN*NN);
  float* Cmv  = (float*)alloc(sizeof(float)*(size_t)BN*NN);
  float* F4   = (float*)alloc(sizeof(float)*(size_t)BN*4*NN);
  float* G    = (float*)alloc(sizeof(float)*(size_t)BN*KK*CC);
  float* Tsc  = (float*)alloc(sizeof(float)*(size_t)BN*NN);
  u16*   spk  = (u16*)alloc(sizeof(u16)*(size_t)BN*NN);           // packed softmax S
  u16*   WD   = (u16*)alloc(sizeof(u16)*(size_t)BN*CC*NN);
  u16*   o2   = (u16*)alloc(sizeof(u16)*(size_t)BN*CC*NN);
  u16*   xf   = (u16*)alloc(sizeof(u16)*(size_t)BN*CC*NN);        // x bf16 B-frag layout
  u16*   wpk  = (u16*)alloc(sizeof(u16)*(size_t)3*16384*8);       // packed w_h/w_m/w_hm
  u16*   wpkE = (u16*)alloc(sizeof(u16)*(size_t)8192*8);          // packed w_e
  u16*   wspk = (u16*)alloc(sizeof(u16)*(size_t)BN*16*64*8);      // packed WS A-frags
  (void)ws_size; (void)in_sizes; (void)n_in; (void)out_size;

  u16* wpkH  = wpk;
  u16* wpkM  = wpk + (size_t)16384*8;
  u16* wpkHM = wpk + (size_t)2*16384*8;

  kw_pack <<<224, 256, 0, stream>>>(w_h, w_m, w_hm, w_e, wpk, wpkE);
  k1_fx   <<<288, 256, 0, stream>>>(x, w_f, w_a2b, F, AMb, Bmv, xf);
  k2_g    <<<512, 256, 0, stream>>>(x, F, G);
  k3_smws <<<8,   256, 0, stream>>>(G, w_beta, wspk);
  k5_conv <<<288, 256, 0, stream>>>(AMb, w1, w3, w5, w7, w_f2c, F4, Cmv);
  k6a_t   <<<8,   256, 0, stream>>>(Bmv, Cmv, Tsc);
  k6b_sm  <<<3,   256, 0, stream>>>(Tsc, spk);
  k7m     <<<1152,256, 0, stream>>>(F4, w_f2d, wpkE, WD);
  k8m     <<<1024,256, 0, stream>>>(WD, spk, x, o2);
  k910    <<<1152,256, 0, stream>>>(o2, xf, F, wspk, wpkH, wpkM, wpkHM, (float*)d_out);
}